// Round 5
// baseline (467.919 us; speedup 1.0000x reference)
//
#include <hip/hip_runtime.h>
#include <math.h>

// EQNetwork on MI355X — R5: wave owns 16 weight-cols x all 64 edges.
// One A-read (weight frag) feeds 4 MFMAs (edge groups in registers: h-frags
// for all 64 edges = 64 VGPRs). LDS A-traffic drops 4x to 1x staged bytes
// (8 ds_read_b128/wave/chunk). Contraction keeps R4's cheap form (i lives in
// quad*4+r -> 1-2 shuffles), looped over edge groups; output col derives
// from wave id -> all cross-wave writes disjoint. 1->1 tables XOR-swizzled
// (i^(e&7)) to break a 16-way float4 read conflict. Numerics = validated
// hi/lo bf16 weight split folded into K=256 (absmax 3.7e-9).

#define NTOT  10000
#define EDGES 160000
#define HD    100
#define NBAS  10

typedef __attribute__((ext_vector_type(8))) short short8;
typedef __attribute__((ext_vector_type(4))) float float4v;

__device__ inline unsigned short f2bf(float x) {
  unsigned u = __builtin_bit_cast(unsigned, x);
  u += 0x7fffu + ((u >> 16) & 1u);          // RNE
  return (unsigned short)(u >> 16);
}
__device__ inline float bf2f(unsigned short b) {
  unsigned u = ((unsigned)b) << 16;
  return __builtin_bit_cast(float, u);
}

// LDS fragment read, MFMA 16x16x32 bf16. Tile = rows of S 16B-slots,
// physical slot = kb ^ (row & 15) -> <=2-way bank aliasing (free).
__device__ inline short8 fragld(const unsigned short* lds, int rbase, int S, int kb, int lane) {
  int r = rbase + (lane & 15);
  int p = kb ^ (r & 15);
  return *(const short8*)(lds + (r * S + p) * 8);
}

// Emit weight image in final LDS layout: groups of 64 rows (weight cols),
// 2048 short8-slots per group, slot = row*32 + (kb ^ (row&15)), element j of
// slot = k' = kb*8+j. k'<128 -> hi(w[k'][n]), k'>=128 -> lo(w[k'-128][n]).
__global__ void prep_bt(const float* __restrict__ w, int Ks, int Ns, int Ngrp,
                        unsigned short* __restrict__ bt) {
  int total = Ngrp * 2048 * 8;
  for (int g = blockIdx.x * 256 + threadIdx.x; g < total; g += gridDim.x * 256) {
    int slot = g >> 3, j = g & 7;
    int grp = slot >> 11, rem = slot & 2047;
    int row = rem >> 5, x = rem & 31;
    int kb = x ^ (row & 15);
    int kp = kb * 8 + j;
    int k = kp & 127;
    int n = grp * 64 + row;
    float v = (k < Ks && n < Ns) ? w[k * Ns + n] : 0.f;
    unsigned short hi = f2bf(v);
    bt[g] = (kp < 128) ? hi : f2bf(v - bf2f(hi));
  }
}

template<int M0I, int M1I, int M0O, int NG, int M1O>
__global__ __launch_bounds__(256, 2) void layer_fused(
    const float* __restrict__ radii, const int* __restrict__ nbr,
    const int* __restrict__ charges,
    const float* __restrict__ f0prev, const float* __restrict__ f1prev,
    const float* __restrict__ w1, const float* __restrict__ b1,
    const unsigned short* __restrict__ bt2, const float* __restrict__ b2,
    const unsigned short* __restrict__ bt3,
    float* __restrict__ f0next, float* __restrict__ f1next)
{
  constexpr int M0T = M0O + NG;
  constexpr int O   = M0T * M0I + M0T * M1I + M1O * M0I + 2 * M1O * M1I;
  constexpr int OFF01  = M0T * M0I;
  constexpr int OFF10  = OFF01 + M0T * M1I;
  constexpr int OFF11A = OFF10 + M1O * M0I;
  constexpr int OFF11B = OFF11A + M1O * M1I;
  constexpr int NCH = (O + 63) / 64;      // L1:1 (zero-padded), L2:13, L3:12

  __shared__ __align__(16) unsigned short bufB[64 * 256];   // 32 KB weight chunk
  __shared__ __align__(16) unsigned short bufA[64 * 128];   // 16 KB h1 -> h2 -> w11 tables
  __shared__ float sh_s[64 * M0T];
  __shared__ float sh_a10[(M1O > 0) ? 64 * M1O : 1];
  __shared__ float sh_v[(M1O > 0) ? 64 * M1O * 3 : 1];
  __shared__ float sh_g0[(M0I > 1) ? 64 * 16 : 64];
  __shared__ float sh_p1[(M1I > 0) ? 64 * 8 : 1];
  __shared__ float sh_u[64 * 3];
  __shared__ float sh_r[64];
  __shared__ int   sh_idx[64];
  __shared__ float w1s[NBAS * HD];
  __shared__ float b1s[HD];
  __shared__ float b2s[128];

  const int tid  = threadIdx.x;
  const int lane = tid & 63, w = tid >> 6;
  const int quad = lane >> 4, ln15 = lane & 15;
  const int eg0  = blockIdx.x * 64;

  // ---- prefetch w2 group 0 (hidden under phase 0) ----
  short8 pref[8];
  {
    const short8* src = (const short8*)bt2;
    #pragma unroll
    for (int i = 0; i < 8; ++i) pref[i] = src[tid + 256 * i];
  }

  // ---- phase 0a ----
  if (tid < 64) {
    float x = radii[(size_t)(eg0 + tid) * 3 + 0];
    float y = radii[(size_t)(eg0 + tid) * 3 + 1];
    float z = radii[(size_t)(eg0 + tid) * 3 + 2];
    float rr = sqrtf(x * x + y * y + z * z);
    float inv = 1.0f / (rr + 1e-8f);
    sh_u[tid * 3 + 0] = x * inv;
    sh_u[tid * 3 + 1] = y * inv;
    sh_u[tid * 3 + 2] = z * inv;
    sh_r[tid] = rr;
    sh_idx[tid] = nbr[eg0 + tid];
  }
  for (int p = tid; p < NBAS * HD; p += 256) w1s[p] = w1[p];
  if (tid < HD) b1s[tid] = b1[tid];
  if (tid < 128) b2s[tid] = (tid < HD) ? b2[tid] : 0.f;
  for (int p = tid; p < 64 * M0T; p += 256) sh_s[p] = 0.f;
  if constexpr (M1O > 0) {
    for (int p = tid; p < 64 * M1O; p += 256)     sh_a10[p] = 0.f;
    for (int p = tid; p < 64 * M1O * 3; p += 256) sh_v[p] = 0.f;
  }
  {
    short8 z = {0, 0, 0, 0, 0, 0, 0, 0};
    #pragma unroll
    for (int i = 0; i < 4; ++i) ((short8*)bufA)[tid + 256 * i] = z;
  }
  __syncthreads();

  // ---- phase 0b: h1 into bufA (A-swizzled bf16); gathers ----
  {
    const int e = tid & 63, jg = tid >> 6;
    const float rr = sh_r[e];
    float bas[NBAS];
    constexpr float STEP = 5.0f / 9.0f;
    #pragma unroll
    for (int nb = 0; nb < NBAS; ++nb) {
      float d = (rr - (float)nb * STEP) / STEP;
      float c = cosf(1.5707964f * d);
      bas[nb] = (fabsf(d) < 1.0f) ? c * c : 0.0f;
    }
    for (int j = jg * 25; j < jg * 25 + 25; ++j) {
      float acc = b1s[j];
      #pragma unroll
      for (int nb = 0; nb < NBAS; ++nb) acc = fmaf(bas[nb], w1s[nb * HD + j], acc);
      int kb = j >> 3;
      bufA[(e * 16 + (kb ^ (e & 15))) * 8 + (j & 7)] = f2bf(fmaxf(acc, 0.f));
    }
  }
  if constexpr (M0I > 1) {
    for (int p = tid; p < 64 * 16; p += 256) {
      int e = p >> 4, i = p & 15;
      sh_g0[p] = 0.5f * f0prev[sh_idx[e] * M0I + i];
    }
  } else {
    if (tid < 64) sh_g0[tid] = 0.5f * ((float)charges[sh_idx[tid]] / 94.0f - 0.5f);
  }
  if constexpr (M1I > 0) {
    for (int p = tid; p < 64 * M1I; p += 256) {
      int e = p >> 3, i = p & 7;
      const float* g = f1prev + (size_t)(sh_idx[e] * M1I + i) * 3;
      sh_p1[p] = 0.5f * (g[0] * sh_u[e * 3] + g[1] * sh_u[e * 3 + 1] + g[2] * sh_u[e * 3 + 2]);
    }
  }
  // write prefetched w2 group 0 -> bufB (linear: image pre-permuted)
  #pragma unroll
  for (int i = 0; i < 8; ++i) ((short8*)bufB)[tid + 256 * i] = pref[i];
  __syncthreads();

  // ---- hoist h1 B-fragments for ALL 4 edge groups (64 VGPRs) ----
  short8 h1f[4][4];
  #pragma unroll
  for (int eg = 0; eg < 4; ++eg)
    #pragma unroll
    for (int kk = 0; kk < 4; ++kk)
      h1f[eg][kk] = fragld(bufA, eg * 16, 16, kk * 4 + quad, lane);
  __syncthreads();   // all hoists done before k2 epilogue rewrites bufA

  // ---- k2: h2 = relu(h1 @ w2split + b2); wave owns 16 cols x 64 edges ----
  #pragma unroll
  for (int t = 0; t < 2; ++t) {
    {  // prefetch: t==0 -> w2 group 1, t==1 -> w3 chunk 0
      const short8* src = (t == 0) ? (const short8*)(bt2 + 16384) : (const short8*)bt3;
      #pragma unroll
      for (int i = 0; i < 8; ++i) pref[i] = src[tid + 256 * i];
    }
    float4v acc[4];
    #pragma unroll
    for (int eg = 0; eg < 4; ++eg) acc[eg] = (float4v){0.f, 0.f, 0.f, 0.f};
    for (int ks = 0; ks < 8; ++ks) {
      short8 af = fragld(bufB, w * 16, 32, ks * 4 + quad, lane);
      #pragma unroll
      for (int eg = 0; eg < 4; ++eg)
        acc[eg] = __builtin_amdgcn_mfma_f32_16x16x32_bf16(af, h1f[eg][ks & 3], acc[eg], 0, 0, 0);
    }
    // epilogue: lane holds h2[e=eg*16+ln15][col=t*64+w*16+quad*4+r]
    #pragma unroll
    for (int eg = 0; eg < 4; ++eg) {
      int e = eg * 16 + ln15;
      #pragma unroll
      for (int p = 0; p < 2; ++p) {
        int col = t * 64 + w * 16 + quad * 4 + 2 * p;
        unsigned lo = f2bf(fmaxf(acc[eg][2 * p]     + b2s[col],     0.f));
        unsigned hi = f2bf(fmaxf(acc[eg][2 * p + 1] + b2s[col + 1], 0.f));
        int kb = col >> 3, j = col & 7;
        *(unsigned*)&bufA[(e * 16 + (kb ^ (e & 15))) * 8 + j] = lo | (hi << 16);
      }
    }
    __syncthreads();
    #pragma unroll
    for (int i = 0; i < 8; ++i) ((short8*)bufB)[tid + 256 * i] = pref[i];
    __syncthreads();
  }

  // ---- hoist h2 B-fragments (all 64 edges); contraction operand regs ----
  short8 h2f[4][4];
  #pragma unroll
  for (int eg = 0; eg < 4; ++eg)
    #pragma unroll
    for (int kk = 0; kk < 4; ++kk)
      h2f[eg][kk] = fragld(bufA, eg * 16, 16, kk * 4 + quad, lane);

  float g0r[4][(M0I > 1) ? 4 : 1];
  float p1r[(M1I > 0) ? 4 : 1][(M1I > 0) ? 4 : 1];
  #pragma unroll
  for (int eg = 0; eg < 4; ++eg) {
    int e = eg * 16 + ln15;
    if constexpr (M0I > 1) {
      #pragma unroll
      for (int r = 0; r < 4; ++r) g0r[eg][r] = sh_g0[e * 16 + quad * 4 + r];
    } else {
      g0r[eg][0] = sh_g0[e];
    }
    if constexpr (M1I > 0) {
      #pragma unroll
      for (int r = 0; r < 4; ++r) p1r[eg][r] = sh_p1[e * 8 + (quad & 1) * 4 + r];
    }
  }

  // ---- (L2) build w11a/w11b tables over bufA (XOR-swizzled slots) ----
  if constexpr (M1O > 0 && M1I > 0) {
    __syncthreads();   // h2f hoists done before table writes clobber bufA
    float4v* w11a = (float4v*)bufA;
    float4v* w11b = w11a + 512;
    for (int p = tid; p < 64 * M1I; p += 256) {
      int e = p >> 3, i = p & 7;
      const float* g = f1prev + (size_t)(sh_idx[e] * M1I + i) * 3;
      float gx = 0.5f * g[0], gy = 0.5f * g[1], gz = 0.5f * g[2];
      float ux = sh_u[e * 3], uy = sh_u[e * 3 + 1], uz = sh_u[e * 3 + 2];
      int slot = e * 8 + (i ^ (e & 7));
      w11a[slot] = (float4v){gx, gy, gz, 0.f};
      w11b[slot] = (float4v){gy * uz - gz * uy, gz * ux - gx * uz, gx * uy - gy * ux, 0.f};
    }
    __syncthreads();
  }

  // ---- k3: W chunks via MFMA + fused contraction ----
  for (int c = 0; c < NCH; ++c) {
    const int c0 = c * 64;
    if (c + 1 < NCH) {
      const short8* src = (const short8*)(bt3 + (size_t)(c + 1) * 16384);
      #pragma unroll
      for (int i = 0; i < 8; ++i) pref[i] = src[tid + 256 * i];
    }
    float4v acc[4];
    #pragma unroll
    for (int eg = 0; eg < 4; ++eg) acc[eg] = (float4v){0.f, 0.f, 0.f, 0.f};
    for (int ks = 0; ks < 8; ++ks) {
      short8 af = fragld(bufB, w * 16, 32, ks * 4 + quad, lane);
      #pragma unroll
      for (int eg = 0; eg < 4; ++eg)
        acc[eg] = __builtin_amdgcn_mfma_f32_16x16x32_bf16(af, h2f[eg][ks & 3], acc[eg], 0, 0, 0);
    }

    // lane holds W[e=eg*16+ln15][col = c0 + w*16 + quad*4 + r]
    if constexpr (M0I == 1) {
      if (w < 2) {                              // cols 0..31 real, rest pad
        #pragma unroll
        for (int eg = 0; eg < 4; ++eg) {
          int e = eg * 16 + ln15;
          #pragma unroll
          for (int r = 0; r < 4; ++r) {
            int col = w * 16 + quad * 4 + r;
            float val = acc[eg][r] * g0r[eg][0];
            if (col < OFF01) sh_s[e * M0T + col] += val;
            else             sh_a10[e * M1O + (col - OFF01)] += val;
          }
        }
      }
    } else {
      if (c0 < OFF01) {                         // 0->0: i = quad*4+r (16-wide)
        const int o = (c0 >> 4) + w;
        float part[4];
        #pragma unroll
        for (int eg = 0; eg < 4; ++eg)
          part[eg] = fmaf(acc[eg][0], g0r[eg][0], fmaf(acc[eg][1], g0r[eg][1],
                     fmaf(acc[eg][2], g0r[eg][2], acc[eg][3] * g0r[eg][3])));
        #pragma unroll
        for (int eg = 0; eg < 4; ++eg) {
          part[eg] += __shfl_xor(part[eg], 16);
          part[eg] += __shfl_xor(part[eg], 32);
        }
        if (quad == 0) {
          #pragma unroll
          for (int eg = 0; eg < 4; ++eg)
            sh_s[(eg * 16 + ln15) * M0T + o] += part[eg];
        }
      } else if (c0 < OFF10) {                  // 1->0: i = (quad&1)*4+r (8-wide)
        const int o = ((c0 - OFF01) >> 3) + 2 * w + (quad >> 1);
        float part[4];
        #pragma unroll
        for (int eg = 0; eg < 4; ++eg)
          part[eg] = fmaf(acc[eg][0], p1r[eg][0], fmaf(acc[eg][1], p1r[eg][1],
                     fmaf(acc[eg][2], p1r[eg][2], acc[eg][3] * p1r[eg][3])));
        #pragma unroll
        for (int eg = 0; eg < 4; ++eg) part[eg] += __shfl_xor(part[eg], 16);
        if ((quad & 1) == 0) {
          #pragma unroll
          for (int eg = 0; eg < 4; ++eg)
            sh_s[(eg * 16 + ln15) * M0T + o] += part[eg];
        }
      } else if constexpr (M1O > 0) {
        if (c0 < OFF11A) {                      // 0->1: like 0->0, target a10
          const int o = ((c0 - OFF10) >> 4) + w;
          float part[4];
          #pragma unroll
          for (int eg = 0; eg < 4; ++eg)
            part[eg] = fmaf(acc[eg][0], g0r[eg][0], fmaf(acc[eg][1], g0r[eg][1],
                       fmaf(acc[eg][2], g0r[eg][2], acc[eg][3] * g0r[eg][3])));
          #pragma unroll
          for (int eg = 0; eg < 4; ++eg) {
            part[eg] += __shfl_xor(part[eg], 16);
            part[eg] += __shfl_xor(part[eg], 32);
          }
          if (quad == 0) {
            #pragma unroll
            for (int eg = 0; eg < 4; ++eg)
              sh_a10[(eg * 16 + ln15) * M1O + o] += part[eg];
          }
        } else {                                // 1->1 a/b: vector, 8-wide
          const bool is_b = (c0 >= OFF11B);
          const float4v* tb = ((const float4v*)bufA) + (is_b ? 512 : 0);
          const int o = ((c0 - (is_b ? OFF11B : OFF11A)) >> 3) + 2 * w + (quad >> 1);
          #pragma unroll
          for (int eg = 0; eg < 4; ++eg) {      // sequential: keeps liveness low
            int e = eg * 16 + ln15;
            float4v tr[4];
            #pragma unroll
            for (int r = 0; r < 4; ++r)
              tr[r] = tb[e * 8 + (((quad & 1) * 4 + r) ^ (e & 7))];
            float px = fmaf(acc[eg][0], tr[0][0], fmaf(acc[eg][1], tr[1][0],
                       fmaf(acc[eg][2], tr[2][0], acc[eg][3] * tr[3][0])));
            float py = fmaf(acc[eg][0], tr[0][1], fmaf(acc[eg][1], tr[1][1],
                       fmaf(acc[eg][2], tr[2][1], acc[eg][3] * tr[3][1])));
            float pz = fmaf(acc[eg][0], tr[0][2], fmaf(acc[eg][1], tr[1][2],
                       fmaf(acc[eg][2], tr[2][2], acc[eg][3] * tr[3][2])));
            px += __shfl_xor(px, 16);
            py += __shfl_xor(py, 16);
            pz += __shfl_xor(pz, 16);
            if ((quad & 1) == 0) {
              sh_v[(e * M1O + o) * 3 + 0] += px;
              sh_v[(e * M1O + o) * 3 + 1] += py;
              sh_v[(e * M1O + o) * 3 + 2] += pz;
            }
          }
        }
      }
    }

    if (c + 1 < NCH) {
      __syncthreads();
      #pragma unroll
      for (int i = 0; i < 8; ++i) ((short8*)bufB)[tid + 256 * i] = pref[i];
      __syncthreads();
    }
  }
  __syncthreads();

  // ---- finalize: mean over K=16, relu / sigmoid gating, write ----
  if (tid < 4 * M0T) {
    const int nl = tid / M0T;
    const int o  = tid - nl * M0T;
    float ssum = 0.0f;
    for (int k = 0; k < 16; ++k) ssum += sh_s[(nl * 16 + k) * M0T + o];
    const float sm = ssum * 0.0625f;
    const int n = blockIdx.x * 4 + nl;
    if (o < M0O) {
      f0next[n * M0O + o] = fmaxf(sm, 0.0f);
    } else if constexpr (M1O > 0) {
      const int og = o - M0O;
      const float gate = 1.0f / (1.0f + expf(-sm));
      float vx = 0.f, vy = 0.f, vz = 0.f;
      for (int k = 0; k < 16; ++k) {
        int e = nl * 16 + k;
        float a = sh_a10[e * M1O + og];
        vx += fmaf(a, sh_u[e * 3 + 0], sh_v[(e * M1O + og) * 3 + 0]);
        vy += fmaf(a, sh_u[e * 3 + 1], sh_v[(e * M1O + og) * 3 + 1]);
        vz += fmaf(a, sh_u[e * 3 + 2], sh_v[(e * M1O + og) * 3 + 2]);
      }
      const float sc = gate * 0.0625f;
      f1next[(n * M1O + og) * 3 + 0] = vx * sc;
      f1next[(n * M1O + og) * 3 + 1] = vy * sc;
      f1next[(n * M1O + og) * 3 + 2] = vz * sc;
    }
  }
}

__global__ void reduce_kernel(const float* __restrict__ f0c, float* __restrict__ out) {
  __shared__ float red[256];
  const int o = blockIdx.x;
  float s = 0.0f;
  for (int n = threadIdx.x; n < NTOT; n += 256) s += f0c[n * 32 + o];
  red[threadIdx.x] = s;
  __syncthreads();
  for (int w = 128; w > 0; w >>= 1) {
    if (threadIdx.x < w) red[threadIdx.x] += red[threadIdx.x + w];
    __syncthreads();
  }
  if (threadIdx.x == 0) out[o] = red[0] / (float)NTOT;
}

extern "C" void kernel_launch(void* const* d_in, const int* in_sizes, int n_in,
                              void* d_out, int out_size, void* d_ws, size_t ws_size,
                              hipStream_t stream) {
  const float* radii   = (const float*)d_in[0];
  const int*   nbr     = (const int*)d_in[1];
  const int*   charges = (const int*)d_in[2];
  const float* w1l[3] = {(const float*)d_in[3],  (const float*)d_in[8],  (const float*)d_in[13]};
  const float* b1l[3] = {(const float*)d_in[4],  (const float*)d_in[9],  (const float*)d_in[14]};
  const float* w2l[3] = {(const float*)d_in[5],  (const float*)d_in[10], (const float*)d_in[15]};
  const float* b2l[3] = {(const float*)d_in[6],  (const float*)d_in[11], (const float*)d_in[16]};
  const float* w3l[3] = {(const float*)d_in[7],  (const float*)d_in[12], (const float*)d_in[17]};

  char* ws = (char*)d_ws;
  size_t off = 0;
  float* f0a = (float*)(ws + off); off += (size_t)NTOT * 16 * 4;
  float* f1a = (float*)(ws + off); off += (size_t)NTOT * 24 * 4;
  float* f0b = (float*)(ws + off); off += (size_t)NTOT * 16 * 4;
  float* f1b = (float*)(ws + off); off += (size_t)NTOT * 24 * 4;
  float* f0c = (float*)(ws + off); off += (size_t)NTOT * 32 * 4;
  unsigned short* bt2  = (unsigned short*)(ws + off); off += (size_t)3 * 2 * 16384 * 2;
  unsigned short* bt31 = (unsigned short*)(ws + off); off += (size_t)1  * 16384 * 2;
  unsigned short* bt32 = (unsigned short*)(ws + off); off += (size_t)13 * 16384 * 2;
  unsigned short* bt33 = (unsigned short*)(ws + off); off += (size_t)12 * 16384 * 2;

  prep_bt<<<128, 256, 0, stream>>>(w2l[0], 100, 100, 2, bt2);
  prep_bt<<<128, 256, 0, stream>>>(w2l[1], 100, 100, 2, bt2 + 32768);
  prep_bt<<<128, 256, 0, stream>>>(w2l[2], 100, 100, 2, bt2 + 65536);
  prep_bt<<<64,  256, 0, stream>>>(w3l[0], 100, 32,  1,  bt31);
  prep_bt<<<832, 256, 0, stream>>>(w3l[1], 100, 832, 13, bt32);
  prep_bt<<<768, 256, 0, stream>>>(w3l[2], 100, 768, 12, bt33);

  constexpr int NBLK = EDGES / 64;   // 2500

  layer_fused<1, 0, 16, 8, 8><<<NBLK, 256, 0, stream>>>(
      radii, nbr, charges, nullptr, nullptr,
      w1l[0], b1l[0], bt2, b2l[0], bt31, f0a, f1a);

  layer_fused<16, 8, 16, 8, 8><<<NBLK, 256, 0, stream>>>(
      radii, nbr, charges, f0a, f1a,
      w1l[1], b1l[1], bt2 + 32768, b2l[1], bt32, f0b, f1b);

  layer_fused<16, 8, 32, 0, 0><<<NBLK, 256, 0, stream>>>(
      radii, nbr, charges, f0b, f1b,
      w1l[2], b1l[2], bt2 + 65536, b2l[2], bt33, f0c, nullptr);

  reduce_kernel<<<32, 256, 0, stream>>>(f0c, (float*)d_out);
}

// Round 6
// 380.290 us; speedup vs baseline: 1.2304x; 1.2304x over previous
//
#include <hip/hip_runtime.h>
#include <math.h>
#include <stdint.h>

// EQNetwork on MI355X — R6: attack DS-instruction-issue (the R5 limiter).
// (1) async global_load_lds weight staging (linear lane-order images; DMA
//     overlaps contraction, drained by s_waitcnt vmcnt(0) before barrier);
// (2) h1 computed by MFMA with K=32 packing the full split product
//     (bas_hi*w_hi | bas_lo*w_hi | bas_hi*w_lo | bias hi/lo) — removes the
//     250 scalar LDS reads/thread of the old h1 build;
// (3) 1->1 / 1->0 operand tables hoisted to registers (cross/dot computed
//     from regs) — no per-chunk table reads;
// (4) first-touch '=' scatter (injective chunk->column maps) + odd-stride
//     padding (25/9/17) to kill 4-8-way bank conflicts.
// Numerics: validated hi/lo bf16 split (absmax ~1e-8 expected).

#define NTOT  10000
#define EDGES 160000
#define HD    100
#define NBAS  10

typedef __attribute__((ext_vector_type(8))) short short8;
typedef __attribute__((ext_vector_type(4))) float float4v;

__device__ inline unsigned short f2bf(float x) {
  unsigned u = __builtin_bit_cast(unsigned, x);
  u += 0x7fffu + ((u >> 16) & 1u);          // RNE
  return (unsigned short)(u >> 16);
}
__device__ inline float bf2f(unsigned short b) {
  unsigned u = ((unsigned)b) << 16;
  return __builtin_bit_cast(float, u);
}

// Async global->LDS DMA, 16 B/lane. LDS dest = wave-uniform base + lane*16;
// gptr is per-lane. Pointer AS casts follow the CK-verified pattern.
__device__ __forceinline__ void dma16(const void* g, void* l) {
  auto gp = (const __attribute__((address_space(1))) unsigned int*)(uintptr_t)g;
  auto lp = (__attribute__((address_space(3))) unsigned int*)(unsigned int)(uintptr_t)l;
  __builtin_amdgcn_global_load_lds(gp, lp, 16, 0, 0);
}
#define WAIT_VM0() __builtin_amdgcn_s_waitcnt(0x0f70)   // vmcnt(0), ignore exp/lgkm

// LDS fragment read, MFMA 16x16x32 bf16. Tile = rows of S 16B-slots,
// physical slot = kb ^ (row & 15) -> <=2-way bank aliasing (free).
__device__ inline short8 fragld(const unsigned short* lds, int rbase, int S, int kb, int lane) {
  int r = rbase + (lane & 15);
  int p = kb ^ (r & 15);
  return *(const short8*)(lds + (r * S + p) * 8);
}

// Weight image for k2/k3 (unchanged format from R5): groups of 64 rows
// (weight cols), slot = row*32 + (kb ^ (row&15)), element j -> k' = kb*8+j;
// k'<128 -> hi(w[k'][n]), k'>=128 -> lo(w[k'-128][n]).
__global__ void prep_bt(const float* __restrict__ w, int Ks, int Ns, int Ngrp,
                        unsigned short* __restrict__ bt) {
  int total = Ngrp * 2048 * 8;
  for (int g = blockIdx.x * 256 + threadIdx.x; g < total; g += gridDim.x * 256) {
    int slot = g >> 3, j = g & 7;
    int grp = slot >> 11, rem = slot & 2047;
    int row = rem >> 5, x = rem & 31;
    int kb = x ^ (row & 15);
    int kp = kb * 8 + j;
    int k = kp & 127;
    float v = (k < Ks && (grp * 64 + row) < Ns) ? w[k * Ns + grp * 64 + row] : 0.f;
    unsigned short hi = f2bf(v);
    bt[g] = (kp < 128) ? hi : f2bf(v - bf2f(hi));
  }
}

// w1 image for the k1 MFMA: 128 rows (h1 cols) x K=32, 4 slots/row,
// phys slot = q ^ (row&3). k: 0..9 hi(w1[k]), 10..19 hi(w1[k-10]),
// 20..29 lo(w1[k-20]), 30 hi(b1), 31 lo(b1).
__global__ void prep_w1(const float* __restrict__ w1, const float* __restrict__ b1,
                        unsigned short* __restrict__ out) {
  int g = blockIdx.x * 256 + threadIdx.x;
  if (g >= 4096) return;
  int s = g >> 3, j = g & 7;
  int row = s >> 2, x = s & 3;
  int q = x ^ (row & 3);
  int k = q * 8 + j;
  int n = row;
  float v = 0.f; int lo = 0;
  if (k < 10)       { v = (n < HD) ? w1[k * HD + n] : 0.f; lo = 0; }
  else if (k < 20)  { v = (n < HD) ? w1[(k - 10) * HD + n] : 0.f; lo = 0; }
  else if (k < 30)  { v = (n < HD) ? w1[(k - 20) * HD + n] : 0.f; lo = 1; }
  else if (k == 30) { v = (n < HD) ? b1[n] : 0.f; lo = 0; }
  else              { v = (n < HD) ? b1[n] : 0.f; lo = 1; }
  unsigned short hi = f2bf(v);
  out[g] = lo ? f2bf(v - bf2f(hi)) : hi;
}

template<int M0I, int M1I, int M0O, int NG, int M1O>
__global__ __launch_bounds__(256, 2) void layer_fused(
    const float* __restrict__ radii, const int* __restrict__ nbr,
    const int* __restrict__ charges,
    const float* __restrict__ f0prev, const float* __restrict__ f1prev,
    const unsigned short* __restrict__ w1i,
    const unsigned short* __restrict__ bt2, const float* __restrict__ b2,
    const unsigned short* __restrict__ bt3,
    float* __restrict__ f0next, float* __restrict__ f1next)
{
  constexpr int M0T = M0O + NG;
  constexpr int O   = M0T * M0I + M0T * M1I + M1O * M0I + 2 * M1O * M1I;
  constexpr int OFF01  = M0T * M0I;
  constexpr int OFF10  = OFF01 + M0T * M1I;
  constexpr int OFF11A = OFF10 + M1O * M0I;
  constexpr int OFF11B = OFF11A + M1O * M1I;
  constexpr int NCH  = (O + 63) / 64;
  constexpr int SSTR = M0T + 1;                       // odd -> conflict-free
  constexpr int ASTR = 9;
  constexpr int VSTR = 25;                            // 8*3+1
  constexpr int GSTR = 17;

  __shared__ __align__(16) unsigned short bufB[64 * 256];   // 32 KB weights
  __shared__ __align__(16) unsigned short bufA[64 * 128];   // 16 KB w1img/basis -> h1 -> h2 -> ta
  __shared__ float sh_s[64 * SSTR];
  __shared__ float sh_a10[(M1O > 0) ? 64 * ASTR : 1];
  __shared__ float sh_v[(M1O > 0 && M1I > 0) ? 64 * VSTR : 1];
  __shared__ float sh_g0[(M0I > 1) ? 64 * GSTR : 64];
  __shared__ float sh_u[64 * 3];
  __shared__ int   sh_idx[64];
  __shared__ float b2s[128];

  const int tid  = threadIdx.x;
  const int lane = tid & 63, w = tid >> 6;
  const int quad = lane >> 4, ln15 = lane & 15;
  const int eg0  = blockIdx.x * 64;

  // ---- issue DMAs: w1 image -> bufA[0:8K), w2 group0 -> bufB ----
  {
    const char* gw1 = (const char*)w1i + (size_t)w * 2048 + lane * 16;
    char* lw1 = (char*)bufA + w * 2048;
    dma16(gw1, lw1);
    dma16(gw1 + 1024, lw1 + 1024);
    const char* gw2 = (const char*)bt2 + (size_t)w * 8192 + lane * 16;
    char* lw2 = (char*)bufB + w * 8192;
    #pragma unroll
    for (int i = 0; i < 8; ++i) dma16(gw2 + i * 1024, lw2 + i * 1024);
  }

  // ---- phase 0: wave 0: geometry + basis tile (bufA[8K:12K)) ----
  if (tid < 64) {
    float x = radii[(size_t)(eg0 + tid) * 3 + 0];
    float y = radii[(size_t)(eg0 + tid) * 3 + 1];
    float z = radii[(size_t)(eg0 + tid) * 3 + 2];
    float rr = sqrtf(x * x + y * y + z * z);
    float inv = 1.0f / (rr + 1e-8f);
    sh_u[tid * 3 + 0] = x * inv;
    sh_u[tid * 3 + 1] = y * inv;
    sh_u[tid * 3 + 2] = z * inv;
    sh_idx[tid] = nbr[eg0 + tid];
    float bas[NBAS];
    constexpr float STEP = 5.0f / 9.0f;
    #pragma unroll
    for (int nb = 0; nb < NBAS; ++nb) {
      float d = (rr - (float)nb * STEP) / STEP;
      float c = cosf(1.5707964f * d);
      bas[nb] = (fabsf(d) < 1.0f) ? c * c : 0.0f;
    }
    unsigned short bh[NBAS], bl[NBAS];
    #pragma unroll
    for (int nb = 0; nb < NBAS; ++nb) {
      bh[nb] = f2bf(bas[nb]);
      bl[nb] = f2bf(bas[nb] - bf2f(bh[nb]));
    }
    const unsigned short ONE = 0x3F80;
    short8 q0 = {(short)bh[0], (short)bh[1], (short)bh[2], (short)bh[3],
                 (short)bh[4], (short)bh[5], (short)bh[6], (short)bh[7]};
    short8 q1 = {(short)bh[8], (short)bh[9], (short)bl[0], (short)bl[1],
                 (short)bl[2], (short)bl[3], (short)bl[4], (short)bl[5]};
    short8 q2 = {(short)bl[6], (short)bl[7], (short)bl[8], (short)bl[9],
                 (short)bh[0], (short)bh[1], (short)bh[2], (short)bh[3]};
    short8 q3 = {(short)bh[4], (short)bh[5], (short)bh[6], (short)bh[7],
                 (short)bh[8], (short)bh[9], (short)ONE, (short)ONE};
    unsigned short* bt = bufA + 4096;      // byte offset 8192
    *(short8*)&bt[(tid * 4 + (0 ^ (tid & 3))) * 8] = q0;
    *(short8*)&bt[(tid * 4 + (1 ^ (tid & 3))) * 8] = q1;
    *(short8*)&bt[(tid * 4 + (2 ^ (tid & 3))) * 8] = q2;
    *(short8*)&bt[(tid * 4 + (3 ^ (tid & 3))) * 8] = q3;
  }
  if (tid < 128) b2s[tid] = (tid < HD) ? b2[tid] : 0.f;
  WAIT_VM0();
  __syncthreads();

  // ---- k1: h1 = relu(basis @ w1split) via MFMA, D[m=col][n=edge] ----
  float4v acc1[2][4];
  {
    short8 basf[4];
    const unsigned short* basT = bufA + 4096;
    #pragma unroll
    for (int eg = 0; eg < 4; ++eg) {
      int e = eg * 16 + ln15;
      basf[eg] = *(const short8*)&basT[(e * 4 + (quad ^ (e & 3))) * 8];
    }
    #pragma unroll
    for (int h = 0; h < 2; ++h) {
      int m = h * 64 + w * 16 + ln15;
      short8 af = *(const short8*)&bufA[(m * 4 + (quad ^ (m & 3))) * 8];
      #pragma unroll
      for (int eg = 0; eg < 4; ++eg) {
        acc1[h][eg] = (h == 0 && false) ? acc1[h][eg] : acc1[h][eg];  // no-op
      }
      #pragma unroll
      for (int eg = 0; eg < 4; ++eg) {
        float4v z4 = {0.f, 0.f, 0.f, 0.f};
        acc1[h][eg] = __builtin_amdgcn_mfma_f32_16x16x32_bf16(af, basf[eg], z4, 0, 0, 0);
      }
    }
  }
  // gathers overlap k1
  if constexpr (M0I > 1) {
    for (int p = tid; p < 64 * 16; p += 256) {
      int e = p >> 4, i = p & 15;
      sh_g0[e * GSTR + i] = 0.5f * f0prev[sh_idx[e] * M0I + i];
    }
  } else {
    if (tid < 64) sh_g0[tid] = 0.5f * ((float)charges[sh_idx[tid]] / 94.0f - 0.5f);
  }
  __syncthreads();   // all waves done reading bufA (img+basis)
  // k1 epilogue: h1 -> bufA, full 64x128 coverage
  #pragma unroll
  for (int h = 0; h < 2; ++h)
    #pragma unroll
    for (int eg = 0; eg < 4; ++eg) {
      int e = eg * 16 + ln15;
      #pragma unroll
      for (int p = 0; p < 2; ++p) {
        int col = h * 64 + w * 16 + quad * 4 + 2 * p;
        unsigned lo = f2bf(fmaxf(acc1[h][eg][2 * p],     0.f));
        unsigned hi = f2bf(fmaxf(acc1[h][eg][2 * p + 1], 0.f));
        int kb = col >> 3, j = col & 7;
        *(unsigned*)&bufA[(e * 16 + (kb ^ (e & 15))) * 8 + j] = lo | (hi << 16);
      }
    }
  __syncthreads();

  // ---- hoist h1 B-fragments (all 64 edges) ----
  short8 h1f[4][4];
  #pragma unroll
  for (int eg = 0; eg < 4; ++eg)
    #pragma unroll
    for (int kk = 0; kk < 4; ++kk)
      h1f[eg][kk] = fragld(bufA, eg * 16, 16, kk * 4 + quad, lane);

  // ---- k2: h2 = relu(h1 @ w2split + b2) ----
  #pragma unroll
  for (int t = 0; t < 2; ++t) {
    float4v acc[4];
    #pragma unroll
    for (int eg = 0; eg < 4; ++eg) acc[eg] = (float4v){0.f, 0.f, 0.f, 0.f};
    for (int ks = 0; ks < 8; ++ks) {
      short8 af = fragld(bufB, w * 16, 32, ks * 4 + quad, lane);
      #pragma unroll
      for (int eg = 0; eg < 4; ++eg)
        acc[eg] = __builtin_amdgcn_mfma_f32_16x16x32_bf16(af, h1f[eg][ks & 3], acc[eg], 0, 0, 0);
    }
    __syncthreads();                       // all waves done reading bufB
    {                                      // DMA next: w2 grp1, then w3 chunk0
      const char* src = (t == 0) ? ((const char*)bt2 + 32768) : (const char*)bt3;
      const char* g = src + (size_t)w * 8192 + lane * 16;
      char* l = (char*)bufB + w * 8192;
      #pragma unroll
      for (int i = 0; i < 8; ++i) dma16(g + i * 1024, l + i * 1024);
    }
    // epilogue overlaps DMA
    {
      int colb = t * 64 + w * 16 + quad * 4;
      float b0 = b2s[colb], b1v = b2s[colb + 1], b2v = b2s[colb + 2], b3 = b2s[colb + 3];
      #pragma unroll
      for (int eg = 0; eg < 4; ++eg) {
        int e = eg * 16 + ln15;
        unsigned l0 = f2bf(fmaxf(acc[eg][0] + b0, 0.f));
        unsigned h0 = f2bf(fmaxf(acc[eg][1] + b1v, 0.f));
        unsigned l1 = f2bf(fmaxf(acc[eg][2] + b2v, 0.f));
        unsigned h1_ = f2bf(fmaxf(acc[eg][3] + b3, 0.f));
        int kb = colb >> 3, j = colb & 7;
        *(unsigned*)&bufA[(e * 16 + (kb ^ (e & 15))) * 8 + j]     = l0 | (h0 << 16);
        int colc = colb + 2, kb2 = colc >> 3, j2 = colc & 7;
        *(unsigned*)&bufA[(e * 16 + (kb2 ^ (e & 15))) * 8 + j2]   = l1 | (h1_ << 16);
      }
    }
    WAIT_VM0();
    __syncthreads();
  }

  // ---- hoist h2 B-fragments ----
  short8 h2f[4][4];
  #pragma unroll
  for (int eg = 0; eg < 4; ++eg)
    #pragma unroll
    for (int kk = 0; kk < 4; ++kk)
      h2f[eg][kk] = fragld(bufA, eg * 16, 16, kk * 4 + quad, lane);

  // ---- ta (0.5*g1) table -> registers; u -> registers; p1 = ta.u ----
  float tax[(M1I > 0) ? 4 : 1][(M1I > 0) ? 4 : 1];
  float tay[(M1I > 0) ? 4 : 1][(M1I > 0) ? 4 : 1];
  float taz[(M1I > 0) ? 4 : 1][(M1I > 0) ? 4 : 1];
  float ux[4], uy[4], uz[4];
  float p1r[(M1I > 0) ? 4 : 1][(M1I > 0) ? 4 : 1];
  if constexpr (M1I > 0) {
    __syncthreads();                       // h2f hoists drained before build
    float4v* tbl = (float4v*)bufA;
    for (int p = tid; p < 64 * M1I; p += 256) {
      int e = p >> 3, i = p & 7;
      const float* g = f1prev + (size_t)(sh_idx[e] * M1I + i) * 3;
      tbl[e * 8 + (i ^ (e & 7))] = (float4v){0.5f * g[0], 0.5f * g[1], 0.5f * g[2], 0.f};
    }
    __syncthreads();
    #pragma unroll
    for (int eg = 0; eg < 4; ++eg) {
      int e = eg * 16 + ln15;
      ux[eg] = sh_u[e * 3 + 0]; uy[eg] = sh_u[e * 3 + 1]; uz[eg] = sh_u[e * 3 + 2];
      #pragma unroll
      for (int r = 0; r < 4; ++r) {
        int i = (quad & 1) * 4 + r;
        float4v tv = tbl[e * 8 + (i ^ (e & 7))];
        tax[eg][r] = tv[0]; tay[eg][r] = tv[1]; taz[eg][r] = tv[2];
        p1r[eg][r] = tv[0] * ux[eg] + tv[1] * uy[eg] + tv[2] * uz[eg];
      }
    }
  }
  float g0r[4][(M0I > 1) ? 4 : 1];
  #pragma unroll
  for (int eg = 0; eg < 4; ++eg) {
    int e = eg * 16 + ln15;
    if constexpr (M0I > 1) {
      #pragma unroll
      for (int r = 0; r < 4; ++r) g0r[eg][r] = sh_g0[e * GSTR + quad * 4 + r];
    } else {
      g0r[eg][0] = sh_g0[e];
    }
  }

  // ---- k3: W chunks via MFMA + fused contraction, DMA under contraction ----
  for (int c = 0; c < NCH; ++c) {
    const int c0 = c * 64;
    float4v acc[4];
    #pragma unroll
    for (int eg = 0; eg < 4; ++eg) acc[eg] = (float4v){0.f, 0.f, 0.f, 0.f};
    for (int ks = 0; ks < 8; ++ks) {
      short8 af = fragld(bufB, w * 16, 32, ks * 4 + quad, lane);
      #pragma unroll
      for (int eg = 0; eg < 4; ++eg)
        acc[eg] = __builtin_amdgcn_mfma_f32_16x16x32_bf16(af, h2f[eg][ks & 3], acc[eg], 0, 0, 0);
    }
    __syncthreads();                       // all waves done reading bufB
    if (c + 1 < NCH) {
      const char* g = (const char*)bt3 + (size_t)(c + 1) * 32768 + (size_t)w * 8192 + lane * 16;
      char* l = (char*)bufB + w * 8192;
      #pragma unroll
      for (int i = 0; i < 8; ++i) dma16(g + i * 1024, l + i * 1024);
    }

    // lane holds W[e=eg*16+ln15][col = c0 + w*16 + quad*4 + r]
    if constexpr (M0I == 1) {
      if (w < 2) {
        #pragma unroll
        for (int eg = 0; eg < 4; ++eg) {
          int e = eg * 16 + ln15;
          #pragma unroll
          for (int r = 0; r < 4; ++r) {
            int col = w * 16 + quad * 4 + r;
            float val = acc[eg][r] * g0r[eg][0];
            if (col < OFF01) sh_s[e * SSTR + col] = val;
            else             sh_a10[e * ASTR + (col - OFF01)] = val;
          }
        }
      }
    } else {
      if (c0 < OFF01) {                     // 0->0: first touch, pure write
        const int o = (c0 >> 4) + w;
        float part[4];
        #pragma unroll
        for (int eg = 0; eg < 4; ++eg)
          part[eg] = fmaf(acc[eg][0], g0r[eg][0], fmaf(acc[eg][1], g0r[eg][1],
                     fmaf(acc[eg][2], g0r[eg][2], acc[eg][3] * g0r[eg][3])));
        #pragma unroll
        for (int eg = 0; eg < 4; ++eg) {
          part[eg] += __shfl_xor(part[eg], 16);
          part[eg] += __shfl_xor(part[eg], 32);
        }
        if (quad == 0) {
          #pragma unroll
          for (int eg = 0; eg < 4; ++eg)
            sh_s[(eg * 16 + ln15) * SSTR + o] = part[eg];
        }
      } else if (c0 < OFF10) {              // 1->0: accumulate
        const int o = ((c0 - OFF01) >> 3) + 2 * w + (quad >> 1);
        float part[4];
        #pragma unroll
        for (int eg = 0; eg < 4; ++eg)
          part[eg] = fmaf(acc[eg][0], p1r[eg][0], fmaf(acc[eg][1], p1r[eg][1],
                     fmaf(acc[eg][2], p1r[eg][2], acc[eg][3] * p1r[eg][3])));
        #pragma unroll
        for (int eg = 0; eg < 4; ++eg) part[eg] += __shfl_xor(part[eg], 16);
        if ((quad & 1) == 0) {
          #pragma unroll
          for (int eg = 0; eg < 4; ++eg)
            sh_s[(eg * 16 + ln15) * SSTR + o] += part[eg];
        }
      } else if constexpr (M1O > 0) {
        if (c0 < OFF11A) {                  // 0->1: first touch, pure write
          const int o = ((c0 - OFF10) >> 4) + w;
          float part[4];
          #pragma unroll
          for (int eg = 0; eg < 4; ++eg)
            part[eg] = fmaf(acc[eg][0], g0r[eg][0], fmaf(acc[eg][1], g0r[eg][1],
                       fmaf(acc[eg][2], g0r[eg][2], acc[eg][3] * g0r[eg][3])));
          #pragma unroll
          for (int eg = 0; eg < 4; ++eg) {
            part[eg] += __shfl_xor(part[eg], 16);
            part[eg] += __shfl_xor(part[eg], 32);
          }
          if (quad == 0) {
            #pragma unroll
            for (int eg = 0; eg < 4; ++eg)
              sh_a10[(eg * 16 + ln15) * ASTR + o] = part[eg];
          }
        } else {                            // 1->1 a (write) / b (accumulate)
          const bool is_b = (c0 >= OFF11B);
          const int o = ((c0 - (is_b ? OFF11B : OFF11A)) >> 3) + 2 * w + (quad >> 1);
          #pragma unroll
          for (int eg = 0; eg < 4; ++eg) {
            int e = eg * 16 + ln15;
            float px = 0.f, py = 0.f, pz = 0.f;
            #pragma unroll
            for (int r = 0; r < 4; ++r) {
              float cx, cy, cz;
              if (is_b) {
                cx = tay[eg][r] * uz[eg] - taz[eg][r] * uy[eg];
                cy = taz[eg][r] * ux[eg] - tax[eg][r] * uz[eg];
                cz = tax[eg][r] * uy[eg] - tay[eg][r] * ux[eg];
              } else {
                cx = tax[eg][r]; cy = tay[eg][r]; cz = taz[eg][r];
              }
              px = fmaf(acc[eg][r], cx, px);
              py = fmaf(acc[eg][r], cy, py);
              pz = fmaf(acc[eg][r], cz, pz);
            }
            px += __shfl_xor(px, 16);
            py += __shfl_xor(py, 16);
            pz += __shfl_xor(pz, 16);
            if ((quad & 1) == 0) {
              float* vp = &sh_v[e * VSTR + o * 3];
              if (is_b) { vp[0] += px; vp[1] += py; vp[2] += pz; }
              else      { vp[0] = px;  vp[1] = py;  vp[2] = pz; }
            }
          }
        }
      }
    }

    if (c + 1 < NCH) {
      WAIT_VM0();
      __syncthreads();
    }
  }
  __syncthreads();

  // ---- finalize: mean over K=16, relu / sigmoid gating, write ----
  if (tid < 4 * M0T) {
    const int nl = tid / M0T;
    const int o  = tid - nl * M0T;
    float ssum = 0.0f;
    for (int k = 0; k < 16; ++k) ssum += sh_s[(nl * 16 + k) * SSTR + o];
    const float sm = ssum * 0.0625f;
    const int n = blockIdx.x * 4 + nl;
    if (o < M0O) {
      f0next[n * M0O + o] = fmaxf(sm, 0.0f);
    } else if constexpr (M1O > 0) {
      const int og = o - M0O;
      const float gate = 1.0f / (1.0f + expf(-sm));
      float vx = 0.f, vy = 0.f, vz = 0.f;
      for (int k = 0; k < 16; ++k) {
        int e = nl * 16 + k;
        float a = sh_a10[e * ASTR + og];
        float bx = 0.f, by = 0.f, bz = 0.f;
        if constexpr (M1I > 0) {
          bx = sh_v[e * VSTR + og * 3 + 0];
          by = sh_v[e * VSTR + og * 3 + 1];
          bz = sh_v[e * VSTR + og * 3 + 2];
        }
        vx += fmaf(a, sh_u[e * 3 + 0], bx);
        vy += fmaf(a, sh_u[e * 3 + 1], by);
        vz += fmaf(a, sh_u[e * 3 + 2], bz);
      }
      const float sc = gate * 0.0625f;
      f1next[(n * M1O + og) * 3 + 0] = vx * sc;
      f1next[(n * M1O + og) * 3 + 1] = vy * sc;
      f1next[(n * M1O + og) * 3 + 2] = vz * sc;
    }
  }
}

__global__ void reduce_kernel(const float* __restrict__ f0c, float* __restrict__ out) {
  __shared__ float red[256];
  const int o = blockIdx.x;
  float s = 0.0f;
  for (int n = threadIdx.x; n < NTOT; n += 256) s += f0c[n * 32 + o];
  red[threadIdx.x] = s;
  __syncthreads();
  for (int w = 128; w > 0; w >>= 1) {
    if (threadIdx.x < w) red[threadIdx.x] += red[threadIdx.x + w];
    __syncthreads();
  }
  if (threadIdx.x == 0) out[o] = red[0] / (float)NTOT;
}

extern "C" void kernel_launch(void* const* d_in, const int* in_sizes, int n_in,
                              void* d_out, int out_size, void* d_ws, size_t ws_size,
                              hipStream_t stream) {
  const float* radii   = (const float*)d_in[0];
  const int*   nbr     = (const int*)d_in[1];
  const int*   charges = (const int*)d_in[2];
  const float* w1l[3] = {(const float*)d_in[3],  (const float*)d_in[8],  (const float*)d_in[13]};
  const float* b1l[3] = {(const float*)d_in[4],  (const float*)d_in[9],  (const float*)d_in[14]};
  const float* w2l[3] = {(const float*)d_in[5],  (const float*)d_in[10], (const float*)d_in[15]};
  const float* b2l[3] = {(const float*)d_in[6],  (const float*)d_in[11], (const float*)d_in[16]};
  const float* w3l[3] = {(const float*)d_in[7],  (const float*)d_in[12], (const float*)d_in[17]};

  char* ws = (char*)d_ws;
  size_t off = 0;
  float* f0a = (float*)(ws + off); off += (size_t)NTOT * 16 * 4;
  float* f1a = (float*)(ws + off); off += (size_t)NTOT * 24 * 4;
  float* f0b = (float*)(ws + off); off += (size_t)NTOT * 16 * 4;
  float* f1b = (float*)(ws + off); off += (size_t)NTOT * 24 * 4;
  float* f0c = (float*)(ws + off); off += (size_t)NTOT * 32 * 4;
  unsigned short* bt2  = (unsigned short*)(ws + off); off += (size_t)3 * 2 * 16384 * 2;
  unsigned short* bt31 = (unsigned short*)(ws + off); off += (size_t)1  * 16384 * 2;
  unsigned short* bt32 = (unsigned short*)(ws + off); off += (size_t)13 * 16384 * 2;
  unsigned short* bt33 = (unsigned short*)(ws + off); off += (size_t)12 * 16384 * 2;
  unsigned short* w1i1 = (unsigned short*)(ws + off); off += (size_t)4096 * 2;
  unsigned short* w1i2 = (unsigned short*)(ws + off); off += (size_t)4096 * 2;
  unsigned short* w1i3 = (unsigned short*)(ws + off); off += (size_t)4096 * 2;

  prep_bt<<<128, 256, 0, stream>>>(w2l[0], 100, 100, 2, bt2);
  prep_bt<<<128, 256, 0, stream>>>(w2l[1], 100, 100, 2, bt2 + 32768);
  prep_bt<<<128, 256, 0, stream>>>(w2l[2], 100, 100, 2, bt2 + 65536);
  prep_bt<<<64,  256, 0, stream>>>(w3l[0], 100, 32,  1,  bt31);
  prep_bt<<<832, 256, 0, stream>>>(w3l[1], 100, 832, 13, bt32);
  prep_bt<<<768, 256, 0, stream>>>(w3l[2], 100, 768, 12, bt33);
  prep_w1<<<16, 256, 0, stream>>>(w1l[0], b1l[0], w1i1);
  prep_w1<<<16, 256, 0, stream>>>(w1l[1], b1l[1], w1i2);
  prep_w1<<<16, 256, 0, stream>>>(w1l[2], b1l[2], w1i3);

  constexpr int NBLK = EDGES / 64;   // 2500

  layer_fused<1, 0, 16, 8, 8><<<NBLK, 256, 0, stream>>>(
      radii, nbr, charges, nullptr, nullptr,
      w1i1, bt2, b2l[0], bt31, f0a, f1a);

  layer_fused<16, 8, 16, 8, 8><<<NBLK, 256, 0, stream>>>(
      radii, nbr, charges, f0a, f1a,
      w1i2, bt2 + 32768, b2l[1], bt32, f0b, f1b);

  layer_fused<16, 8, 32, 0, 0><<<NBLK, 256, 0, stream>>>(
      radii, nbr, charges, f0b, f1b,
      w1i3, bt2 + 65536, b2l[2], bt33, f0c, nullptr);

  reduce_kernel<<<32, 256, 0, stream>>>(f0c, (float*)d_out);
}

// Round 7
// 362.927 us; speedup vs baseline: 1.2893x; 1.0478x over previous
//
#include <hip/hip_runtime.h>
#include <math.h>
#include <stdint.h>

// EQNetwork on MI355X — R7: barrier-free K-loops.
// bufB is wave-private (wave w reads/DMAs only rows [16w,16w+16)), so the two
// per-chunk __syncthreads() of R6 protect nothing -> removed. Per chunk:
// vmcnt(0) [own DMA landed] -> fragld x8 to regs -> lgkmcnt(0) -> issue DMA
// for chunk c+1 into own segment (a full chunk of MFMA+contraction to land)
// -> MFMA from regs -> contraction. Waves free-run; pipes interleave.
// Scatter safety without barriers: the 1->0 '+=' lands on the same wave that
// did the 0->0 '=' via a column permutation baked into the weight image
// (o = 8t + w + 4h, writer wave = o mod 4) -> same-wave DS program order.
// 1->1a/b already same-wave (o = 2w+h both). All else single-touch '='.
// Numerics: validated hi/lo bf16 split folded into K=256 (absmax 3.7e-9).

#define NTOT  10000
#define EDGES 160000
#define HD    100
#define NBAS  10

typedef __attribute__((ext_vector_type(8))) short short8;
typedef __attribute__((ext_vector_type(4))) float float4v;

__device__ inline unsigned short f2bf(float x) {
  unsigned u = __builtin_bit_cast(unsigned, x);
  u += 0x7fffu + ((u >> 16) & 1u);          // RNE
  return (unsigned short)(u >> 16);
}
__device__ inline float bf2f(unsigned short b) {
  unsigned u = ((unsigned)b) << 16;
  return __builtin_bit_cast(float, u);
}

// Async global->LDS DMA, 16 B/lane.
__device__ __forceinline__ void dma16(const void* g, void* l) {
  auto gp = (const __attribute__((address_space(1))) unsigned int*)(uintptr_t)g;
  auto lp = (__attribute__((address_space(3))) unsigned int*)(unsigned int)(uintptr_t)l;
  __builtin_amdgcn_global_load_lds(gp, lp, 16, 0, 0);
}
#define WAIT_VM0()  __builtin_amdgcn_s_waitcnt(0x0F70)   // vmcnt(0) only
#define WAIT_LGKM() __builtin_amdgcn_s_waitcnt(0xC07F)   // lgkmcnt(0) only

// LDS fragment read, MFMA 16x16x32 bf16. Tile = rows of S 16B-slots,
// physical slot = kb ^ (row & 15) -> <=2-way bank aliasing (free).
__device__ inline short8 fragld(const unsigned short* lds, int rbase, int S, int kb, int lane) {
  int r = rbase + (lane & 15);
  int p = kb ^ (r & 15);
  return *(const short8*)(lds + (r * S + p) * 8);
}

// Weight image (R5 format) + 1->0 same-wave permutation: for image column cg
// in [off01, off10): t=(cg-off01)>>6, w=(cg&63)>>4, quad=(cg>>2)&3, r=cg&3,
// o=8t+w+4(quad>>1), i=(quad&1)*4+r, source col = off01 + o*8 + i.
// Elsewhere identity. slot = row*32 + (kb ^ (row&15)), element j -> k'=kb*8+j;
// k'<128 -> hi(w[k'][n]), k'>=128 -> lo(w[k'-128][n]).
__global__ void prep_bt(const float* __restrict__ w, int Ks, int Ns, int Ngrp,
                        int off01, int off10, unsigned short* __restrict__ bt) {
  int total = Ngrp * 2048 * 8;
  for (int g = blockIdx.x * 256 + threadIdx.x; g < total; g += gridDim.x * 256) {
    int slot = g >> 3, j = g & 7;
    int grp = slot >> 11, rem = slot & 2047;
    int row = rem >> 5, x = rem & 31;
    int kb = x ^ (row & 15);
    int kp = kb * 8 + j;
    int k = kp & 127;
    int cg = grp * 64 + row;
    int n = cg;
    if (cg >= off01 && cg < off10) {
      int cl = cg & 63;
      int wv = cl >> 4, qd = (cl >> 2) & 3, r = cl & 3;
      int t = (cg - off01) >> 6;
      int o = 8 * t + wv + 4 * (qd >> 1);
      int i = (qd & 1) * 4 + r;
      n = off01 + o * 8 + i;
    }
    float v = (k < Ks && n < Ns) ? w[k * Ns + n] : 0.f;
    unsigned short hi = f2bf(v);
    bt[g] = (kp < 128) ? hi : f2bf(v - bf2f(hi));
  }
}

// w1 image for the k1 MFMA: 128 rows (h1 cols) x K=32, 4 slots/row,
// phys slot = q ^ (row&3). k: 0..9 hi(w1[k]), 10..19 hi(w1[k-10]),
// 20..29 lo(w1[k-20]), 30 hi(b1), 31 lo(b1).
__global__ void prep_w1(const float* __restrict__ w1, const float* __restrict__ b1,
                        unsigned short* __restrict__ out) {
  int g = blockIdx.x * 256 + threadIdx.x;
  if (g >= 4096) return;
  int s = g >> 3, j = g & 7;
  int row = s >> 2, x = s & 3;
  int q = x ^ (row & 3);
  int k = q * 8 + j;
  int n = row;
  float v = 0.f; int lo = 0;
  if (k < 10)       { v = (n < HD) ? w1[k * HD + n] : 0.f; lo = 0; }
  else if (k < 20)  { v = (n < HD) ? w1[(k - 10) * HD + n] : 0.f; lo = 0; }
  else if (k < 30)  { v = (n < HD) ? w1[(k - 20) * HD + n] : 0.f; lo = 1; }
  else if (k == 30) { v = (n < HD) ? b1[n] : 0.f; lo = 0; }
  else              { v = (n < HD) ? b1[n] : 0.f; lo = 1; }
  unsigned short hi = f2bf(v);
  out[g] = lo ? f2bf(v - bf2f(hi)) : hi;
}

template<int M0I, int M1I, int M0O, int NG, int M1O>
__global__ __launch_bounds__(256, 2) void layer_fused(
    const float* __restrict__ radii, const int* __restrict__ nbr,
    const int* __restrict__ charges,
    const float* __restrict__ f0prev, const float* __restrict__ f1prev,
    const unsigned short* __restrict__ w1i,
    const unsigned short* __restrict__ bt2, const float* __restrict__ b2,
    const unsigned short* __restrict__ bt3,
    float* __restrict__ f0next, float* __restrict__ f1next)
{
  constexpr int M0T = M0O + NG;
  constexpr int O   = M0T * M0I + M0T * M1I + M1O * M0I + 2 * M1O * M1I;
  constexpr int OFF01  = M0T * M0I;
  constexpr int OFF10  = OFF01 + M0T * M1I;
  constexpr int OFF11A = OFF10 + M1O * M0I;
  constexpr int OFF11B = OFF11A + M1O * M1I;
  constexpr int NCH  = (O + 63) / 64;
  constexpr int SSTR = M0T + 1;
  constexpr int ASTR = 9;
  constexpr int VSTR = 25;
  constexpr int GSTR = 17;

  __shared__ __align__(16) unsigned short bufB[64 * 256];   // 32 KB, wave-private segs
  __shared__ __align__(16) unsigned short bufA[64 * 128];   // 16 KB w1img/basis -> h1 -> h2 -> ta
  __shared__ float sh_s[64 * SSTR];
  __shared__ float sh_a10[(M1O > 0) ? 64 * ASTR : 1];
  __shared__ float sh_v[(M1O > 0 && M1I > 0) ? 64 * VSTR : 1];
  __shared__ float sh_g0[(M0I > 1) ? 64 * GSTR : 64];
  __shared__ float sh_u[64 * 3];
  __shared__ int   sh_idx[64];
  __shared__ float b2s[128];

  const int tid  = threadIdx.x;
  const int lane = tid & 63, w = tid >> 6;
  const int quad = lane >> 4, ln15 = lane & 15;
  const int eg0  = blockIdx.x * 64;

  // ---- issue DMAs: w1 image -> bufA[0:8K), w2 group0 -> bufB (own segs) ----
  {
    const char* gw1 = (const char*)w1i + (size_t)w * 2048 + lane * 16;
    char* lw1 = (char*)bufA + w * 2048;
    dma16(gw1, lw1);
    dma16(gw1 + 1024, lw1 + 1024);
    const char* gw2 = (const char*)bt2 + (size_t)w * 8192 + lane * 16;
    char* lw2 = (char*)bufB + w * 8192;
    #pragma unroll
    for (int i = 0; i < 8; ++i) dma16(gw2 + i * 1024, lw2 + i * 1024);
  }

  // ---- phase 0: wave 0: geometry + basis tile (bufA[8K:12K)) ----
  if (tid < 64) {
    float x = radii[(size_t)(eg0 + tid) * 3 + 0];
    float y = radii[(size_t)(eg0 + tid) * 3 + 1];
    float z = radii[(size_t)(eg0 + tid) * 3 + 2];
    float rr = sqrtf(x * x + y * y + z * z);
    float inv = 1.0f / (rr + 1e-8f);
    sh_u[tid * 3 + 0] = x * inv;
    sh_u[tid * 3 + 1] = y * inv;
    sh_u[tid * 3 + 2] = z * inv;
    sh_idx[tid] = nbr[eg0 + tid];
    float bas[NBAS];
    constexpr float STEP = 5.0f / 9.0f;
    #pragma unroll
    for (int nb = 0; nb < NBAS; ++nb) {
      float d = (rr - (float)nb * STEP) / STEP;
      float c = cosf(1.5707964f * d);
      bas[nb] = (fabsf(d) < 1.0f) ? c * c : 0.0f;
    }
    unsigned short bh[NBAS], bl[NBAS];
    #pragma unroll
    for (int nb = 0; nb < NBAS; ++nb) {
      bh[nb] = f2bf(bas[nb]);
      bl[nb] = f2bf(bas[nb] - bf2f(bh[nb]));
    }
    const unsigned short ONE = 0x3F80;
    short8 q0 = {(short)bh[0], (short)bh[1], (short)bh[2], (short)bh[3],
                 (short)bh[4], (short)bh[5], (short)bh[6], (short)bh[7]};
    short8 q1 = {(short)bh[8], (short)bh[9], (short)bl[0], (short)bl[1],
                 (short)bl[2], (short)bl[3], (short)bl[4], (short)bl[5]};
    short8 q2 = {(short)bl[6], (short)bl[7], (short)bl[8], (short)bl[9],
                 (short)bh[0], (short)bh[1], (short)bh[2], (short)bh[3]};
    short8 q3 = {(short)bh[4], (short)bh[5], (short)bh[6], (short)bh[7],
                 (short)bh[8], (short)bh[9], (short)ONE, (short)ONE};
    unsigned short* bt = bufA + 4096;
    *(short8*)&bt[(tid * 4 + (0 ^ (tid & 3))) * 8] = q0;
    *(short8*)&bt[(tid * 4 + (1 ^ (tid & 3))) * 8] = q1;
    *(short8*)&bt[(tid * 4 + (2 ^ (tid & 3))) * 8] = q2;
    *(short8*)&bt[(tid * 4 + (3 ^ (tid & 3))) * 8] = q3;
  }
  if (tid < 128) b2s[tid] = (tid < HD) ? b2[tid] : 0.f;
  WAIT_VM0();
  __syncthreads();

  // ---- k1: h1 = relu(basis @ w1split) via MFMA, D[m=col][n=edge] ----
  float4v acc1[2][4];
  {
    short8 basf[4];
    const unsigned short* basT = bufA + 4096;
    #pragma unroll
    for (int eg = 0; eg < 4; ++eg) {
      int e = eg * 16 + ln15;
      basf[eg] = *(const short8*)&basT[(e * 4 + (quad ^ (e & 3))) * 8];
    }
    #pragma unroll
    for (int h = 0; h < 2; ++h) {
      int m = h * 64 + w * 16 + ln15;
      short8 af = *(const short8*)&bufA[(m * 4 + (quad ^ (m & 3))) * 8];
      #pragma unroll
      for (int eg = 0; eg < 4; ++eg) {
        float4v z4 = {0.f, 0.f, 0.f, 0.f};
        acc1[h][eg] = __builtin_amdgcn_mfma_f32_16x16x32_bf16(af, basf[eg], z4, 0, 0, 0);
      }
    }
  }
  // gathers overlap k1
  if constexpr (M0I > 1) {
    for (int p = tid; p < 64 * 16; p += 256) {
      int e = p >> 4, i = p & 15;
      sh_g0[e * GSTR + i] = 0.5f * f0prev[sh_idx[e] * M0I + i];
    }
  } else {
    if (tid < 64) sh_g0[tid] = 0.5f * ((float)charges[sh_idx[tid]] / 94.0f - 0.5f);
  }
  __syncthreads();   // all waves done reading bufA (img+basis)
  // k1 epilogue: h1 -> bufA
  #pragma unroll
  for (int h = 0; h < 2; ++h)
    #pragma unroll
    for (int eg = 0; eg < 4; ++eg) {
      int e = eg * 16 + ln15;
      #pragma unroll
      for (int p = 0; p < 2; ++p) {
        int col = h * 64 + w * 16 + quad * 4 + 2 * p;
        unsigned lo = f2bf(fmaxf(acc1[h][eg][2 * p],     0.f));
        unsigned hi = f2bf(fmaxf(acc1[h][eg][2 * p + 1], 0.f));
        int kb = col >> 3, j = col & 7;
        *(unsigned*)&bufA[(e * 16 + (kb ^ (e & 15))) * 8 + j] = lo | (hi << 16);
      }
    }
  __syncthreads();

  // ---- hoist h1 B-fragments (all 64 edges) ----
  short8 h1f[4][4];
  #pragma unroll
  for (int eg = 0; eg < 4; ++eg)
    #pragma unroll
    for (int kk = 0; kk < 4; ++kk)
      h1f[eg][kk] = fragld(bufA, eg * 16, 16, kk * 4 + quad, lane);
  __syncthreads();   // all hoists done before t=0 epilogue rewrites bufA

  // ---- k2: h2 = relu(h1 @ w2split + b2); barrier-free bufB ----
  #pragma unroll
  for (int t = 0; t < 2; ++t) {
    WAIT_VM0();                            // own w2 group-t segment landed
    short8 bf[8];
    #pragma unroll
    for (int ks = 0; ks < 8; ++ks) bf[ks] = fragld(bufB, w * 16, 32, ks * 4 + quad, lane);
    WAIT_LGKM();                           // reads drained before overwrite
    {                                      // DMA next: w2 grp1, then w3 chunk0
      const char* src = (t == 0) ? ((const char*)bt2 + 32768) : (const char*)bt3;
      const char* g = src + (size_t)w * 8192 + lane * 16;
      char* l = (char*)bufB + w * 8192;
      #pragma unroll
      for (int i = 0; i < 8; ++i) dma16(g + i * 1024, l + i * 1024);
    }
    float4v acc[4];
    #pragma unroll
    for (int eg = 0; eg < 4; ++eg) acc[eg] = (float4v){0.f, 0.f, 0.f, 0.f};
    #pragma unroll
    for (int ks = 0; ks < 8; ++ks)
      #pragma unroll
      for (int eg = 0; eg < 4; ++eg)
        acc[eg] = __builtin_amdgcn_mfma_f32_16x16x32_bf16(bf[ks], h1f[eg][ks & 3], acc[eg], 0, 0, 0);
    // epilogue: h2[e][col] -> bufA (disjoint bytes across waves/t)
    {
      int colb = t * 64 + w * 16 + quad * 4;
      float b0 = b2s[colb], b1v = b2s[colb + 1], b2v = b2s[colb + 2], b3 = b2s[colb + 3];
      #pragma unroll
      for (int eg = 0; eg < 4; ++eg) {
        int e = eg * 16 + ln15;
        unsigned l0 = f2bf(fmaxf(acc[eg][0] + b0, 0.f));
        unsigned h0 = f2bf(fmaxf(acc[eg][1] + b1v, 0.f));
        unsigned l1 = f2bf(fmaxf(acc[eg][2] + b2v, 0.f));
        unsigned h1_ = f2bf(fmaxf(acc[eg][3] + b3, 0.f));
        int kb = colb >> 3, j = colb & 7;
        *(unsigned*)&bufA[(e * 16 + (kb ^ (e & 15))) * 8 + j]   = l0 | (h0 << 16);
        int colc = colb + 2, kb2 = colc >> 3, j2 = colc & 7;
        *(unsigned*)&bufA[(e * 16 + (kb2 ^ (e & 15))) * 8 + j2] = l1 | (h1_ << 16);
      }
    }
  }
  __syncthreads();   // h2 tile complete

  // ---- hoist h2 B-fragments ----
  short8 h2f[4][4];
  #pragma unroll
  for (int eg = 0; eg < 4; ++eg)
    #pragma unroll
    for (int kk = 0; kk < 4; ++kk)
      h2f[eg][kk] = fragld(bufA, eg * 16, 16, kk * 4 + quad, lane);

  // ---- ta (0.5*g1) table + contraction operand regs ----
  float tax[(M1I > 0) ? 4 : 1][(M1I > 0) ? 4 : 1];
  float tay[(M1I > 0) ? 4 : 1][(M1I > 0) ? 4 : 1];
  float taz[(M1I > 0) ? 4 : 1][(M1I > 0) ? 4 : 1];
  float ux[4], uy[4], uz[4];
  float p1r[(M1I > 0) ? 4 : 1][(M1I > 0) ? 4 : 1];
  if constexpr (M1I > 0) {
    __syncthreads();                       // h2f hoists drained before build
    float4v* tbl = (float4v*)bufA;
    for (int p = tid; p < 64 * M1I; p += 256) {
      int e = p >> 3, i = p & 7;
      const float* g = f1prev + (size_t)(sh_idx[e] * M1I + i) * 3;
      tbl[e * 8 + (i ^ (e & 7))] = (float4v){0.5f * g[0], 0.5f * g[1], 0.5f * g[2], 0.f};
    }
    __syncthreads();
    #pragma unroll
    for (int eg = 0; eg < 4; ++eg) {
      int e = eg * 16 + ln15;
      ux[eg] = sh_u[e * 3 + 0]; uy[eg] = sh_u[e * 3 + 1]; uz[eg] = sh_u[e * 3 + 2];
      #pragma unroll
      for (int r = 0; r < 4; ++r) {
        int i = (quad & 1) * 4 + r;
        float4v tv = tbl[e * 8 + (i ^ (e & 7))];
        tax[eg][r] = tv[0]; tay[eg][r] = tv[1]; taz[eg][r] = tv[2];
        p1r[eg][r] = tv[0] * ux[eg] + tv[1] * uy[eg] + tv[2] * uz[eg];
      }
    }
  }
  float g0r[4][(M0I > 1) ? 4 : 1];
  #pragma unroll
  for (int eg = 0; eg < 4; ++eg) {
    int e = eg * 16 + ln15;
    if constexpr (M0I > 1) {
      #pragma unroll
      for (int r = 0; r < 4; ++r) g0r[eg][r] = sh_g0[e * GSTR + quad * 4 + r];
    } else {
      g0r[eg][0] = sh_g0[e];
    }
  }

  // ---- k3: barrier-free chunk loop ----
  for (int c = 0; c < NCH; ++c) {
    const int c0 = c * 64;
    WAIT_VM0();                            // own chunk-c segment landed
    short8 bf[8];
    #pragma unroll
    for (int ks = 0; ks < 8; ++ks) bf[ks] = fragld(bufB, w * 16, 32, ks * 4 + quad, lane);
    WAIT_LGKM();                           // reads drained before overwrite
    if (c + 1 < NCH) {
      const char* g = (const char*)bt3 + (size_t)(c + 1) * 32768 + (size_t)w * 8192 + lane * 16;
      char* l = (char*)bufB + w * 8192;
      #pragma unroll
      for (int i = 0; i < 8; ++i) dma16(g + i * 1024, l + i * 1024);
    }
    float4v acc[4];
    #pragma unroll
    for (int eg = 0; eg < 4; ++eg) acc[eg] = (float4v){0.f, 0.f, 0.f, 0.f};
    #pragma unroll
    for (int ks = 0; ks < 8; ++ks)
      #pragma unroll
      for (int eg = 0; eg < 4; ++eg)
        acc[eg] = __builtin_amdgcn_mfma_f32_16x16x32_bf16(bf[ks], h2f[eg][ks & 3], acc[eg], 0, 0, 0);

    // lane holds W[e=eg*16+ln15][col = c0 + w*16 + quad*4 + r]
    if constexpr (M0I == 1) {
      if (w < 2) {
        #pragma unroll
        for (int eg = 0; eg < 4; ++eg) {
          int e = eg * 16 + ln15;
          #pragma unroll
          for (int r = 0; r < 4; ++r) {
            int col = w * 16 + quad * 4 + r;
            float val = acc[eg][r] * g0r[eg][0];
            if (col < OFF01) sh_s[e * SSTR + col] = val;
            else             sh_a10[e * ASTR + (col - OFF01)] = val;
          }
        }
      }
    } else {
      if (c0 < OFF01) {                     // 0->0: first touch '='
        const int o = (c0 >> 4) + w;
        float part[4];
        #pragma unroll
        for (int eg = 0; eg < 4; ++eg)
          part[eg] = fmaf(acc[eg][0], g0r[eg][0], fmaf(acc[eg][1], g0r[eg][1],
                     fmaf(acc[eg][2], g0r[eg][2], acc[eg][3] * g0r[eg][3])));
        #pragma unroll
        for (int eg = 0; eg < 4; ++eg) {
          part[eg] += __shfl_xor(part[eg], 16);
          part[eg] += __shfl_xor(part[eg], 32);
        }
        if (quad == 0) {
          #pragma unroll
          for (int eg = 0; eg < 4; ++eg)
            sh_s[(eg * 16 + ln15) * SSTR + o] = part[eg];
        }
      } else if (c0 < OFF10) {              // 1->0: '+=' same-wave as its '='
        const int t = (c0 - OFF01) >> 6;
        const int o = 8 * t + w + 4 * (quad >> 1);
        float part[4];
        #pragma unroll
        for (int eg = 0; eg < 4; ++eg)
          part[eg] = fmaf(acc[eg][0], p1r[eg][0], fmaf(acc[eg][1], p1r[eg][1],
                     fmaf(acc[eg][2], p1r[eg][2], acc[eg][3] * p1r[eg][3])));
        #pragma unroll
        for (int eg = 0; eg < 4; ++eg) part[eg] += __shfl_xor(part[eg], 16);
        if ((quad & 1) == 0) {
          #pragma unroll
          for (int eg = 0; eg < 4; ++eg)
            sh_s[(eg * 16 + ln15) * SSTR + o] += part[eg];
        }
      } else if constexpr (M1O > 0) {
        if (c0 < OFF11A) {                  // 0->1: first touch '='
          const int o = ((c0 - OFF10) >> 4) + w;
          float part[4];
          #pragma unroll
          for (int eg = 0; eg < 4; ++eg)
            part[eg] = fmaf(acc[eg][0], g0r[eg][0], fmaf(acc[eg][1], g0r[eg][1],
                       fmaf(acc[eg][2], g0r[eg][2], acc[eg][3] * g0r[eg][3])));
          #pragma unroll
          for (int eg = 0; eg < 4; ++eg) {
            part[eg] += __shfl_xor(part[eg], 16);
            part[eg] += __shfl_xor(part[eg], 32);
          }
          if (quad == 0) {
            #pragma unroll
            for (int eg = 0; eg < 4; ++eg)
              sh_a10[(eg * 16 + ln15) * ASTR + o] = part[eg];
          }
        } else {                            // 1->1 a '=' then b '+=' (same wave/lanes)
          const bool is_b = (c0 >= OFF11B);
          const int o = ((c0 - (is_b ? OFF11B : OFF11A)) >> 3) + 2 * w + (quad >> 1);
          #pragma unroll
          for (int eg = 0; eg < 4; ++eg) {
            int e = eg * 16 + ln15;
            float px = 0.f, py = 0.f, pz = 0.f;
            #pragma unroll
            for (int r = 0; r < 4; ++r) {
              float cx, cy, cz;
              if (is_b) {
                cx = tay[eg][r] * uz[eg] - taz[eg][r] * uy[eg];
                cy = taz[eg][r] * ux[eg] - tax[eg][r] * uz[eg];
                cz = tax[eg][r] * uy[eg] - tay[eg][r] * ux[eg];
              } else {
                cx = tax[eg][r]; cy = tay[eg][r]; cz = taz[eg][r];
              }
              px = fmaf(acc[eg][r], cx, px);
              py = fmaf(acc[eg][r], cy, py);
              pz = fmaf(acc[eg][r], cz, pz);
            }
            px += __shfl_xor(px, 16);
            py += __shfl_xor(py, 16);
            pz += __shfl_xor(pz, 16);
            if ((quad & 1) == 0) {
              float* vp = &sh_v[e * VSTR + o * 3];
              if (is_b) { vp[0] += px; vp[1] += py; vp[2] += pz; }
              else      { vp[0] = px;  vp[1] = py;  vp[2] = pz; }
            }
          }
        }
      }
    }
  }
  __syncthreads();

  // ---- finalize: mean over K=16, relu / sigmoid gating, write ----
  if (tid < 4 * M0T) {
    const int nl = tid / M0T;
    const int o  = tid - nl * M0T;
    float ssum = 0.0f;
    for (int k = 0; k < 16; ++k) ssum += sh_s[(nl * 16 + k) * SSTR + o];
    const float sm = ssum * 0.0625f;
    const int n = blockIdx.x * 4 + nl;
    if (o < M0O) {
      f0next[n * M0O + o] = fmaxf(sm, 0.0f);
    } else if constexpr (M1O > 0) {
      const int og = o - M0O;
      const float gate = 1.0f / (1.0f + expf(-sm));
      float vx = 0.f, vy = 0.f, vz = 0.f;
      for (int k = 0; k < 16; ++k) {
        int e = nl * 16 + k;
        float a = sh_a10[e * ASTR + og];
        float bx = 0.f, by = 0.f, bz = 0.f;
        if constexpr (M1I > 0) {
          bx = sh_v[e * VSTR + og * 3 + 0];
          by = sh_v[e * VSTR + og * 3 + 1];
          bz = sh_v[e * VSTR + og * 3 + 2];
        }
        vx += fmaf(a, sh_u[e * 3 + 0], bx);
        vy += fmaf(a, sh_u[e * 3 + 1], by);
        vz += fmaf(a, sh_u[e * 3 + 2], bz);
      }
      const float sc = gate * 0.0625f;
      f1next[(n * M1O + og) * 3 + 0] = vx * sc;
      f1next[(n * M1O + og) * 3 + 1] = vy * sc;
      f1next[(n * M1O + og) * 3 + 2] = vz * sc;
    }
  }
}

__global__ void reduce_kernel(const float* __restrict__ f0c, float* __restrict__ out) {
  __shared__ float red[256];
  const int o = blockIdx.x;
  float s = 0.0f;
  for (int n = threadIdx.x; n < NTOT; n += 256) s += f0c[n * 32 + o];
  red[threadIdx.x] = s;
  __syncthreads();
  for (int w = 128; w > 0; w >>= 1) {
    if (threadIdx.x < w) red[threadIdx.x] += red[threadIdx.x + w];
    __syncthreads();
  }
  if (threadIdx.x == 0) out[o] = red[0] / (float)NTOT;
}

extern "C" void kernel_launch(void* const* d_in, const int* in_sizes, int n_in,
                              void* d_out, int out_size, void* d_ws, size_t ws_size,
                              hipStream_t stream) {
  const float* radii   = (const float*)d_in[0];
  const int*   nbr     = (const int*)d_in[1];
  const int*   charges = (const int*)d_in[2];
  const float* w1l[3] = {(const float*)d_in[3],  (const float*)d_in[8],  (const float*)d_in[13]};
  const float* b1l[3] = {(const float*)d_in[4],  (const float*)d_in[9],  (const float*)d_in[14]};
  const float* w2l[3] = {(const float*)d_in[5],  (const float*)d_in[10], (const float*)d_in[15]};
  const float* b2l[3] = {(const float*)d_in[6],  (const float*)d_in[11], (const float*)d_in[16]};
  const float* w3l[3] = {(const float*)d_in[7],  (const float*)d_in[12], (const float*)d_in[17]};

  char* ws = (char*)d_ws;
  size_t off = 0;
  float* f0a = (float*)(ws + off); off += (size_t)NTOT * 16 * 4;
  float* f1a = (float*)(ws + off); off += (size_t)NTOT * 24 * 4;
  float* f0b = (float*)(ws + off); off += (size_t)NTOT * 16 * 4;
  float* f1b = (float*)(ws + off); off += (size_t)NTOT * 24 * 4;
  float* f0c = (float*)(ws + off); off += (size_t)NTOT * 32 * 4;
  unsigned short* bt2  = (unsigned short*)(ws + off); off += (size_t)3 * 2 * 16384 * 2;
  unsigned short* bt31 = (unsigned short*)(ws + off); off += (size_t)1  * 16384 * 2;
  unsigned short* bt32 = (unsigned short*)(ws + off); off += (size_t)13 * 16384 * 2;
  unsigned short* bt33 = (unsigned short*)(ws + off); off += (size_t)12 * 16384 * 2;
  unsigned short* w1i1 = (unsigned short*)(ws + off); off += (size_t)4096 * 2;
  unsigned short* w1i2 = (unsigned short*)(ws + off); off += (size_t)4096 * 2;
  unsigned short* w1i3 = (unsigned short*)(ws + off); off += (size_t)4096 * 2;

  prep_bt<<<128, 256, 0, stream>>>(w2l[0], 100, 100, 2, 0, 0, bt2);
  prep_bt<<<128, 256, 0, stream>>>(w2l[1], 100, 100, 2, 0, 0, bt2 + 32768);
  prep_bt<<<128, 256, 0, stream>>>(w2l[2], 100, 100, 2, 0, 0, bt2 + 65536);
  prep_bt<<<64,  256, 0, stream>>>(w3l[0], 100, 32,  1,  0,   0,   bt31);
  prep_bt<<<832, 256, 0, stream>>>(w3l[1], 100, 832, 13, 384, 576, bt32);
  prep_bt<<<768, 256, 0, stream>>>(w3l[2], 100, 768, 12, 512, 768, bt33);
  prep_w1<<<16, 256, 0, stream>>>(w1l[0], b1l[0], w1i1);
  prep_w1<<<16, 256, 0, stream>>>(w1l[1], b1l[1], w1i2);
  prep_w1<<<16, 256, 0, stream>>>(w1l[2], b1l[2], w1i3);

  constexpr int NBLK = EDGES / 64;   // 2500

  layer_fused<1, 0, 16, 8, 8><<<NBLK, 256, 0, stream>>>(
      radii, nbr, charges, nullptr, nullptr,
      w1i1, bt2, b2l[0], bt31, f0a, f1a);

  layer_fused<16, 8, 16, 8, 8><<<NBLK, 256, 0, stream>>>(
      radii, nbr, charges, f0a, f1a,
      w1i2, bt2 + 32768, b2l[1], bt32, f0b, f1b);

  layer_fused<16, 8, 32, 0, 0><<<NBLK, 256, 0, stream>>>(
      radii, nbr, charges, f0b, f1b,
      w1i3, bt2 + 65536, b2l[2], bt33, f0c, nullptr);

  reduce_kernel<<<32, 256, 0, stream>>>(f0c, (float*)d_out);
}

// Round 8
// 274.017 us; speedup vs baseline: 1.7076x; 1.3245x over previous
//
#include <hip/hip_runtime.h>
#include <math.h>
#include <stdint.h>

// EQNetwork on MI355X — R8: hi-only bf16 w2/w3 (K=128) + 3 blocks/CU.
// Rationale: R7 showed per-edge bf16 noise averages out ~100x in the final
// node-mean (absmax 3.7e-9 vs 2.5e-6 threshold); only systematic weight error
// matters. hi-only w2/w3 gives ~0.2% systematic -> predicted absmax ~1e-6,
// inside threshold. This halves MFMA, fragld, and DMA, and shrinks bufB to
// 16 KB (4 KB wave-private segments). sh_g0 (pre-k1 transient) and sh_v
// (k3-only) overlay dead bufA regions -> LDS 42 KB -> 3 blocks/CU (12 waves)
// for real cross-wave pipe overlap. w1+basis keep the exact hi/lo K=32 pack.
// Barrier-free wave-private bufB loops retained from R7; 1->0 '+=' same-wave
// ordering via column permutation baked into the weight image.

#define NTOT  10000
#define EDGES 160000
#define HD    100
#define NBAS  10

typedef __attribute__((ext_vector_type(8))) short short8;
typedef __attribute__((ext_vector_type(4))) float float4v;

__device__ inline unsigned short f2bf(float x) {
  unsigned u = __builtin_bit_cast(unsigned, x);
  u += 0x7fffu + ((u >> 16) & 1u);          // RNE
  return (unsigned short)(u >> 16);
}
__device__ inline float bf2f(unsigned short b) {
  unsigned u = ((unsigned)b) << 16;
  return __builtin_bit_cast(float, u);
}

// Async global->LDS DMA, 16 B/lane.
__device__ __forceinline__ void dma16(const void* g, void* l) {
  auto gp = (const __attribute__((address_space(1))) unsigned int*)(uintptr_t)g;
  auto lp = (__attribute__((address_space(3))) unsigned int*)(unsigned int)(uintptr_t)l;
  __builtin_amdgcn_global_load_lds(gp, lp, 16, 0, 0);
}
#define WAIT_VM0()  __builtin_amdgcn_s_waitcnt(0x0F70)   // vmcnt(0) only
#define WAIT_LGKM() __builtin_amdgcn_s_waitcnt(0xC07F)   // lgkmcnt(0) only

// LDS fragment read, MFMA 16x16x32 bf16. Tile = rows of S 16B-slots,
// physical slot = kb ^ (row & 15) -> <=2-way bank aliasing (free).
__device__ inline short8 fragld(const unsigned short* lds, int rbase, int S, int kb, int lane) {
  int r = rbase + (lane & 15);
  int p = kb ^ (r & 15);
  return *(const short8*)(lds + (r * S + p) * 8);
}

// hi-only weight image element: groups of 64 rows (weight cols), 1024
// short8-slots/group, slot = row*16 + (kb ^ (row&15)), element j -> k=kb*8+j
// (0..127). 1->0 same-wave permutation on cols in [off01, off10).
__device__ inline unsigned short bt_elem(const float* __restrict__ w, int Ks, int Ns,
                                         int off01, int off10, int g) {
  int slot = g >> 3, j = g & 7;
  int grp = slot >> 10, rem = slot & 1023;
  int row = rem >> 4, x = rem & 15;
  int kb = x ^ (row & 15);
  int k = kb * 8 + j;
  int cg = grp * 64 + row, n = cg;
  if (cg >= off01 && cg < off10) {
    int cl = cg & 63;
    int wv = cl >> 4, qd = (cl >> 2) & 3, r = cl & 3;
    int t = (cg - off01) >> 6;
    n = off01 + (8 * t + wv + 4 * (qd >> 1)) * 8 + (qd & 1) * 4 + r;
  }
  float v = (k < Ks && n < Ns) ? w[k * Ns + n] : 0.f;
  return f2bf(v);
}

// w1 image for the k1 MFMA (exact hi/lo): 128 rows x K=32, 4 slots/row,
// phys slot = q ^ (row&3). k: 0..9 hi(w1), 10..19 hi(w1), 20..29 lo(w1),
// 30 hi(b1), 31 lo(b1).
__device__ inline unsigned short w1_elem(const float* __restrict__ w1,
                                         const float* __restrict__ b1, int g) {
  int s = g >> 3, j = g & 7;
  int row = s >> 2, x = s & 3;
  int q = x ^ (row & 3);
  int k = q * 8 + j;
  int n = row;
  float v = 0.f; int lo = 0;
  if (k < 10)       { v = (n < HD) ? w1[k * HD + n] : 0.f; lo = 0; }
  else if (k < 20)  { v = (n < HD) ? w1[(k - 10) * HD + n] : 0.f; lo = 0; }
  else if (k < 30)  { v = (n < HD) ? w1[(k - 20) * HD + n] : 0.f; lo = 1; }
  else if (k == 30) { v = (n < HD) ? b1[n] : 0.f; lo = 0; }
  else              { v = (n < HD) ? b1[n] : 0.f; lo = 1; }
  unsigned short hi = f2bf(v);
  return lo ? f2bf(v - bf2f(hi)) : hi;
}

// Single fused prep kernel (was 9 launches).
// Segments: w2 imgs 3x16384 | w3-1 8192 | w3-2 106496 | w3-3 98304 | w1 imgs 3x4096.
__global__ void prep_all(const float* __restrict__ w2a, const float* __restrict__ w2b,
                         const float* __restrict__ w2c,
                         const float* __restrict__ w3a, const float* __restrict__ w3b,
                         const float* __restrict__ w3c,
                         const float* __restrict__ w1a, const float* __restrict__ w1b,
                         const float* __restrict__ w1c,
                         const float* __restrict__ b1a, const float* __restrict__ b1b,
                         const float* __restrict__ b1c,
                         unsigned short* __restrict__ bt2, unsigned short* __restrict__ bt31,
                         unsigned short* __restrict__ bt32, unsigned short* __restrict__ bt33,
                         unsigned short* __restrict__ w1i1, unsigned short* __restrict__ w1i2,
                         unsigned short* __restrict__ w1i3) {
  int g = blockIdx.x * 256 + threadIdx.x;
  if (g < 16384) { bt2[g]         = bt_elem(w2a, 100, 100, 0, 0, g); return; }  g -= 16384;
  if (g < 16384) { bt2[16384 + g] = bt_elem(w2b, 100, 100, 0, 0, g); return; }  g -= 16384;
  if (g < 16384) { bt2[32768 + g] = bt_elem(w2c, 100, 100, 0, 0, g); return; }  g -= 16384;
  if (g < 8192)  { bt31[g] = bt_elem(w3a, 100, 32,  0,   0,   g); return; }     g -= 8192;
  if (g < 106496){ bt32[g] = bt_elem(w3b, 100, 832, 384, 576, g); return; }     g -= 106496;
  if (g < 98304) { bt33[g] = bt_elem(w3c, 100, 768, 512, 768, g); return; }     g -= 98304;
  if (g < 4096)  { w1i1[g] = w1_elem(w1a, b1a, g); return; }                    g -= 4096;
  if (g < 4096)  { w1i2[g] = w1_elem(w1b, b1b, g); return; }                    g -= 4096;
  if (g < 4096)  { w1i3[g] = w1_elem(w1c, b1c, g); }
}

template<int M0I, int M1I, int M0O, int NG, int M1O>
__global__ __launch_bounds__(256, 4) void layer_fused(
    const float* __restrict__ radii, const int* __restrict__ nbr,
    const int* __restrict__ charges,
    const float* __restrict__ f0prev, const float* __restrict__ f1prev,
    const unsigned short* __restrict__ w1i,
    const unsigned short* __restrict__ bt2, const float* __restrict__ b2,
    const unsigned short* __restrict__ bt3,
    float* __restrict__ f0next, float* __restrict__ f1next)
{
  constexpr int M0T = M0O + NG;
  constexpr int O   = M0T * M0I + M0T * M1I + M1O * M0I + 2 * M1O * M1I;
  constexpr int OFF01  = M0T * M0I;
  constexpr int OFF10  = OFF01 + M0T * M1I;
  constexpr int OFF11A = OFF10 + M1O * M0I;
  constexpr int OFF11B = OFF11A + M1O * M1I;
  constexpr int NCH  = (O + 63) / 64;
  constexpr int SSTR = M0T + 1;
  constexpr int ASTR = 9;
  constexpr int VSTR = 25;

  __shared__ __align__(16) unsigned short bufB[64 * 128];   // 16 KB, wave-private 4 KB segs
  __shared__ __align__(16) unsigned short bufA[64 * 128];   // 16 KB multi-use
  __shared__ float sh_s[64 * SSTR];
  __shared__ float sh_a10[(M1O > 0) ? 64 * ASTR : 1];
  __shared__ float sh_u[64 * 3];
  __shared__ int   sh_idx[64];
  __shared__ float b2s[128];

  float* sh_g0f = (float*)(bufA + 6144);   // bytes [12288,16384): transient (pre-k1)
  float* sh_vf  = (float*)(bufA + 4096);   // bytes [8192,14592): k3-only overlay

  const int tid  = threadIdx.x;
  const int lane = tid & 63, w = tid >> 6;
  const int quad = lane >> 4, ln15 = lane & 15;
  const int eg0  = blockIdx.x * 64;

  // ---- issue DMAs: w1 image -> bufA[0:8K), w2 group0 -> bufB (own segs) ----
  {
    const char* gw1 = (const char*)w1i + (size_t)w * 2048 + lane * 16;
    char* lw1 = (char*)bufA + w * 2048;
    dma16(gw1, lw1);
    dma16(gw1 + 1024, lw1 + 1024);
    const char* gw2 = (const char*)bt2 + (size_t)w * 4096 + lane * 16;
    char* lw2 = (char*)bufB + w * 4096;
    #pragma unroll
    for (int i = 0; i < 4; ++i) dma16(gw2 + i * 1024, lw2 + i * 1024);
  }

  // ---- phase 0: wave 0: geometry + basis tile (bufA bytes [8192,12288)) ----
  if (tid < 64) {
    float x = radii[(size_t)(eg0 + tid) * 3 + 0];
    float y = radii[(size_t)(eg0 + tid) * 3 + 1];
    float z = radii[(size_t)(eg0 + tid) * 3 + 2];
    float rr = sqrtf(x * x + y * y + z * z);
    float inv = 1.0f / (rr + 1e-8f);
    sh_u[tid * 3 + 0] = x * inv;
    sh_u[tid * 3 + 1] = y * inv;
    sh_u[tid * 3 + 2] = z * inv;
    sh_idx[tid] = nbr[eg0 + tid];
    float bas[NBAS];
    constexpr float STEP = 5.0f / 9.0f;
    #pragma unroll
    for (int nb = 0; nb < NBAS; ++nb) {
      float d = (rr - (float)nb * STEP) / STEP;
      float c = cosf(1.5707964f * d);
      bas[nb] = (fabsf(d) < 1.0f) ? c * c : 0.0f;
    }
    unsigned short bh[NBAS], bl[NBAS];
    #pragma unroll
    for (int nb = 0; nb < NBAS; ++nb) {
      bh[nb] = f2bf(bas[nb]);
      bl[nb] = f2bf(bas[nb] - bf2f(bh[nb]));
    }
    const unsigned short ONE = 0x3F80;
    short8 q0 = {(short)bh[0], (short)bh[1], (short)bh[2], (short)bh[3],
                 (short)bh[4], (short)bh[5], (short)bh[6], (short)bh[7]};
    short8 q1 = {(short)bh[8], (short)bh[9], (short)bl[0], (short)bl[1],
                 (short)bl[2], (short)bl[3], (short)bl[4], (short)bl[5]};
    short8 q2 = {(short)bl[6], (short)bl[7], (short)bl[8], (short)bl[9],
                 (short)bh[0], (short)bh[1], (short)bh[2], (short)bh[3]};
    short8 q3 = {(short)bh[4], (short)bh[5], (short)bh[6], (short)bh[7],
                 (short)bh[8], (short)bh[9], (short)ONE, (short)ONE};
    unsigned short* bt = bufA + 4096;
    *(short8*)&bt[(tid * 4 + (0 ^ (tid & 3))) * 8] = q0;
    *(short8*)&bt[(tid * 4 + (1 ^ (tid & 3))) * 8] = q1;
    *(short8*)&bt[(tid * 4 + (2 ^ (tid & 3))) * 8] = q2;
    *(short8*)&bt[(tid * 4 + (3 ^ (tid & 3))) * 8] = q3;
  }
  if (tid < 128) b2s[tid] = (tid < HD) ? b2[tid] : 0.f;
  WAIT_VM0();
  __syncthreads();                          // sync1: w1img + basis + idx ready

  // ---- k1: h1 = relu(basis @ w1split) via MFMA; g0 gather overlaps ----
  float4v acc1[2][4];
  {
    short8 basf[4];
    const unsigned short* basT = bufA + 4096;
    #pragma unroll
    for (int eg = 0; eg < 4; ++eg) {
      int e = eg * 16 + ln15;
      basf[eg] = *(const short8*)&basT[(e * 4 + (quad ^ (e & 3))) * 8];
    }
    #pragma unroll
    for (int h = 0; h < 2; ++h) {
      int m = h * 64 + w * 16 + ln15;
      short8 af = *(const short8*)&bufA[(m * 4 + (quad ^ (m & 3))) * 8];
      #pragma unroll
      for (int eg = 0; eg < 4; ++eg) {
        float4v z4 = {0.f, 0.f, 0.f, 0.f};
        acc1[h][eg] = __builtin_amdgcn_mfma_f32_16x16x32_bf16(af, basf[eg], z4, 0, 0, 0);
      }
    }
  }
  if constexpr (M0I > 1) {
    #pragma unroll
    for (int it = 0; it < 4; ++it) {
      int p = tid + 256 * it;
      int e = p >> 4, i = p & 15;
      sh_g0f[p] = 0.5f * f0prev[sh_idx[e] * M0I + i];
    }
  } else {
    if (tid < 64) sh_g0f[tid] = 0.5f * ((float)charges[sh_idx[tid]] / 94.0f - 0.5f);
  }
  __syncthreads();                          // sync2: gather done; k1 reads done

  // ---- hoist g0 to registers (before h1 overwrites bufA) ----
  float g0r[4][(M0I > 1) ? 4 : 1];
  #pragma unroll
  for (int eg = 0; eg < 4; ++eg) {
    int e = eg * 16 + ln15;
    if constexpr (M0I > 1) {
      #pragma unroll
      for (int r = 0; r < 4; ++r) g0r[eg][r] = sh_g0f[e * 16 + quad * 4 + r];
    } else {
      g0r[eg][0] = sh_g0f[e];
    }
  }
  __syncthreads();                          // sync3: hoists done

  // k1 epilogue: h1 -> bufA (full 16 KB, A-swizzled)
  #pragma unroll
  for (int h = 0; h < 2; ++h)
    #pragma unroll
    for (int eg = 0; eg < 4; ++eg) {
      int e = eg * 16 + ln15;
      #pragma unroll
      for (int p = 0; p < 2; ++p) {
        int col = h * 64 + w * 16 + quad * 4 + 2 * p;
        unsigned lo = f2bf(fmaxf(acc1[h][eg][2 * p],     0.f));
        unsigned hi = f2bf(fmaxf(acc1[h][eg][2 * p + 1], 0.f));
        int kb = col >> 3, j = col & 7;
        *(unsigned*)&bufA[(e * 16 + (kb ^ (e & 15))) * 8 + j] = lo | (hi << 16);
      }
    }
  __syncthreads();                          // sync4: h1 complete

  // ---- hoist h1 B-fragments (all 64 edges, K=128) ----
  short8 h1f[4][4];
  #pragma unroll
  for (int eg = 0; eg < 4; ++eg)
    #pragma unroll
    for (int kk = 0; kk < 4; ++kk)
      h1f[eg][kk] = fragld(bufA, eg * 16, 16, kk * 4 + quad, lane);
  __syncthreads();                          // sync5: hoists done before k2 epilogue

  // ---- k2: h2 = relu(h1 @ w2hi + b2); barrier-free wave-private bufB ----
  #pragma unroll
  for (int t = 0; t < 2; ++t) {
    WAIT_VM0();                             // own w2 group-t segment landed
    short8 bf[4];
    #pragma unroll
    for (int ks = 0; ks < 4; ++ks) bf[ks] = fragld(bufB, w * 16, 16, ks * 4 + quad, lane);
    WAIT_LGKM();                            // reads drained before overwrite
    {                                       // DMA next: w2 grp1, then w3 chunk0
      const char* src = (t == 0) ? ((const char*)bt2 + 16384) : (const char*)bt3;
      const char* g = src + (size_t)w * 4096 + lane * 16;
      char* l = (char*)bufB + w * 4096;
      #pragma unroll
      for (int i = 0; i < 4; ++i) dma16(g + i * 1024, l + i * 1024);
    }
    float4v acc[4];
    #pragma unroll
    for (int eg = 0; eg < 4; ++eg) acc[eg] = (float4v){0.f, 0.f, 0.f, 0.f};
    #pragma unroll
    for (int ks = 0; ks < 4; ++ks)
      #pragma unroll
      for (int eg = 0; eg < 4; ++eg)
        acc[eg] = __builtin_amdgcn_mfma_f32_16x16x32_bf16(bf[ks], h1f[eg][ks], acc[eg], 0, 0, 0);
    {
      int colb = t * 64 + w * 16 + quad * 4;
      float b0 = b2s[colb], b1v = b2s[colb + 1], b2v = b2s[colb + 2], b3 = b2s[colb + 3];
      #pragma unroll
      for (int eg = 0; eg < 4; ++eg) {
        int e = eg * 16 + ln15;
        unsigned l0 = f2bf(fmaxf(acc[eg][0] + b0, 0.f));
        unsigned h0 = f2bf(fmaxf(acc[eg][1] + b1v, 0.f));
        unsigned l1 = f2bf(fmaxf(acc[eg][2] + b2v, 0.f));
        unsigned h1_ = f2bf(fmaxf(acc[eg][3] + b3, 0.f));
        int kb = colb >> 3, j = colb & 7;
        *(unsigned*)&bufA[(e * 16 + (kb ^ (e & 15))) * 8 + j]   = l0 | (h0 << 16);
        int colc = colb + 2, kb2 = colc >> 3, j2 = colc & 7;
        *(unsigned*)&bufA[(e * 16 + (kb2 ^ (e & 15))) * 8 + j2] = l1 | (h1_ << 16);
      }
    }
  }
  __syncthreads();                          // sync6: h2 tile complete

  // ---- hoist h2 B-fragments ----
  short8 h2f[4][4];
  #pragma unroll
  for (int eg = 0; eg < 4; ++eg)
    #pragma unroll
    for (int kk = 0; kk < 4; ++kk)
      h2f[eg][kk] = fragld(bufA, eg * 16, 16, kk * 4 + quad, lane);

  // ---- ta (0.5*g1) table -> regs; u -> regs; p1 = ta.u ----
  float tax[(M1I > 0) ? 4 : 1][(M1I > 0) ? 4 : 1];
  float tay[(M1I > 0) ? 4 : 1][(M1I > 0) ? 4 : 1];
  float taz[(M1I > 0) ? 4 : 1][(M1I > 0) ? 4 : 1];
  float ux[4], uy[4], uz[4];
  float p1r[(M1I > 0) ? 4 : 1][(M1I > 0) ? 4 : 1];
  if constexpr (M1I > 0) {
    __syncthreads();                        // h2f hoists drained before table build
    float4v* tbl = (float4v*)bufA;          // bytes [0:8192)
    #pragma unroll
    for (int it = 0; it < 2; ++it) {
      int p = tid + 256 * it;
      int e = p >> 3, i = p & 7;
      const float* g = f1prev + (size_t)(sh_idx[e] * M1I + i) * 3;
      tbl[e * 8 + (i ^ (e & 7))] = (float4v){0.5f * g[0], 0.5f * g[1], 0.5f * g[2], 0.f};
    }
    __syncthreads();
    #pragma unroll
    for (int eg = 0; eg < 4; ++eg) {
      int e = eg * 16 + ln15;
      ux[eg] = sh_u[e * 3 + 0]; uy[eg] = sh_u[e * 3 + 1]; uz[eg] = sh_u[e * 3 + 2];
      #pragma unroll
      for (int r = 0; r < 4; ++r) {
        int i = (quad & 1) * 4 + r;
        float4v tv = tbl[e * 8 + (i ^ (e & 7))];
        tax[eg][r] = tv[0]; tay[eg][r] = tv[1]; taz[eg][r] = tv[2];
        p1r[eg][r] = tv[0] * ux[eg] + tv[1] * uy[eg] + tv[2] * uz[eg];
      }
    }
    __syncthreads();                        // ta reads done (sh_vf writes follow in k3)
  }

  // ---- k3: barrier-free chunk loop (K=128) ----
  for (int c = 0; c < NCH; ++c) {
    const int c0 = c * 64;
    WAIT_VM0();                             // own chunk-c segment landed
    short8 bf[4];
    #pragma unroll
    for (int ks = 0; ks < 4; ++ks) bf[ks] = fragld(bufB, w * 16, 16, ks * 4 + quad, lane);
    WAIT_LGKM();                            // reads drained before overwrite
    if (c + 1 < NCH) {
      const char* g = (const char*)bt3 + (size_t)(c + 1) * 16384 + (size_t)w * 4096 + lane * 16;
      char* l = (char*)bufB + w * 4096;
      #pragma unroll
      for (int i = 0; i < 4; ++i) dma16(g + i * 1024, l + i * 1024);
    }
    float4v acc[4];
    #pragma unroll
    for (int eg = 0; eg < 4; ++eg) acc[eg] = (float4v){0.f, 0.f, 0.f, 0.f};
    #pragma unroll
    for (int ks = 0; ks < 4; ++ks)
      #pragma unroll
      for (int eg = 0; eg < 4; ++eg)
        acc[eg] = __builtin_amdgcn_mfma_f32_16x16x32_bf16(bf[ks], h2f[eg][ks], acc[eg], 0, 0, 0);

    // lane holds W[e=eg*16+ln15][col = c0 + w*16 + quad*4 + r]
    if constexpr (M0I == 1) {
      if (w < 2) {
        #pragma unroll
        for (int eg = 0; eg < 4; ++eg) {
          int e = eg * 16 + ln15;
          #pragma unroll
          for (int r = 0; r < 4; ++r) {
            int col = w * 16 + quad * 4 + r;
            float val = acc[eg][r] * g0r[eg][0];
            if (col < OFF01) sh_s[e * SSTR + col] = val;
            else             sh_a10[e * ASTR + (col - OFF01)] = val;
          }
        }
      }
    } else {
      if (c0 < OFF01) {                     // 0->0: first touch '='
        const int o = (c0 >> 4) + w;
        float part[4];
        #pragma unroll
        for (int eg = 0; eg < 4; ++eg)
          part[eg] = fmaf(acc[eg][0], g0r[eg][0], fmaf(acc[eg][1], g0r[eg][1],
                     fmaf(acc[eg][2], g0r[eg][2], acc[eg][3] * g0r[eg][3])));
        #pragma unroll
        for (int eg = 0; eg < 4; ++eg) {
          part[eg] += __shfl_xor(part[eg], 16);
          part[eg] += __shfl_xor(part[eg], 32);
        }
        if (quad == 0) {
          #pragma unroll
          for (int eg = 0; eg < 4; ++eg)
            sh_s[(eg * 16 + ln15) * SSTR + o] = part[eg];
        }
      } else if (c0 < OFF10) {              // 1->0: '+=' same-wave as its '='
        const int t = (c0 - OFF01) >> 6;
        const int o = 8 * t + w + 4 * (quad >> 1);
        float part[4];
        #pragma unroll
        for (int eg = 0; eg < 4; ++eg)
          part[eg] = fmaf(acc[eg][0], p1r[eg][0], fmaf(acc[eg][1], p1r[eg][1],
                     fmaf(acc[eg][2], p1r[eg][2], acc[eg][3] * p1r[eg][3])));
        #pragma unroll
        for (int eg = 0; eg < 4; ++eg) part[eg] += __shfl_xor(part[eg], 16);
        if ((quad & 1) == 0) {
          #pragma unroll
          for (int eg = 0; eg < 4; ++eg)
            sh_s[(eg * 16 + ln15) * SSTR + o] += part[eg];
        }
      } else if constexpr (M1O > 0) {
        if (c0 < OFF11A) {                  // 0->1: first touch '='
          const int o = ((c0 - OFF10) >> 4) + w;
          float part[4];
          #pragma unroll
          for (int eg = 0; eg < 4; ++eg)
            part[eg] = fmaf(acc[eg][0], g0r[eg][0], fmaf(acc[eg][1], g0r[eg][1],
                       fmaf(acc[eg][2], g0r[eg][2], acc[eg][3] * g0r[eg][3])));
          #pragma unroll
          for (int eg = 0; eg < 4; ++eg) {
            part[eg] += __shfl_xor(part[eg], 16);
            part[eg] += __shfl_xor(part[eg], 32);
          }
          if (quad == 0) {
            #pragma unroll
            for (int eg = 0; eg < 4; ++eg)
              sh_a10[(eg * 16 + ln15) * ASTR + o] = part[eg];
          }
        } else {                            // 1->1 a '=' then b '+=' (same wave/lanes)
          const bool is_b = (c0 >= OFF11B);
          const int o = ((c0 - (is_b ? OFF11B : OFF11A)) >> 3) + 2 * w + (quad >> 1);
          #pragma unroll
          for (int eg = 0; eg < 4; ++eg) {
            int e = eg * 16 + ln15;
            float px = 0.f, py = 0.f, pz = 0.f;
            #pragma unroll
            for (int r = 0; r < 4; ++r) {
              float cx, cy, cz;
              if (is_b) {
                cx = tay[eg][r] * uz[eg] - taz[eg][r] * uy[eg];
                cy = taz[eg][r] * ux[eg] - tax[eg][r] * uz[eg];
                cz = tax[eg][r] * uy[eg] - tay[eg][r] * ux[eg];
              } else {
                cx = tax[eg][r]; cy = tay[eg][r]; cz = taz[eg][r];
              }
              px = fmaf(acc[eg][r], cx, px);
              py = fmaf(acc[eg][r], cy, py);
              pz = fmaf(acc[eg][r], cz, pz);
            }
            px += __shfl_xor(px, 16);
            py += __shfl_xor(py, 16);
            pz += __shfl_xor(pz, 16);
            if ((quad & 1) == 0) {
              float* vp = &sh_vf[e * VSTR + o * 3];
              if (is_b) { vp[0] += px; vp[1] += py; vp[2] += pz; }
              else      { vp[0] = px;  vp[1] = py;  vp[2] = pz; }
            }
          }
        }
      }
    }
  }
  __syncthreads();

  // ---- finalize: mean over K=16, relu / sigmoid gating, write ----
  if (tid < 4 * M0T) {
    const int nl = tid / M0T;
    const int o  = tid - nl * M0T;
    float ssum = 0.0f;
    for (int k = 0; k < 16; ++k) ssum += sh_s[(nl * 16 + k) * SSTR + o];
    const float sm = ssum * 0.0625f;
    const int n = blockIdx.x * 4 + nl;
    if (o < M0O) {
      f0next[n * M0O + o] = fmaxf(sm, 0.0f);
    } else if constexpr (M1O > 0) {
      const int og = o - M0O;
      const float gate = 1.0f / (1.0f + expf(-sm));
      float vx = 0.f, vy = 0.f, vz = 0.f;
      for (int k = 0; k < 16; ++k) {
        int e = nl * 16 + k;
        float a = sh_a10[e * ASTR + og];
        float bx = 0.f, by = 0.f, bz = 0.f;
        if constexpr (M1I > 0) {
          bx = sh_vf[e * VSTR + og * 3 + 0];
          by = sh_vf[e * VSTR + og * 3 + 1];
          bz = sh_vf[e * VSTR + og * 3 + 2];
        }
        vx += fmaf(a, sh_u[e * 3 + 0], bx);
        vy += fmaf(a, sh_u[e * 3 + 1], by);
        vz += fmaf(a, sh_u[e * 3 + 2], bz);
      }
      const float sc = gate * 0.0625f;
      f1next[(n * M1O + og) * 3 + 0] = vx * sc;
      f1next[(n * M1O + og) * 3 + 1] = vy * sc;
      f1next[(n * M1O + og) * 3 + 2] = vz * sc;
    }
  }
}

__global__ void reduce_kernel(const float* __restrict__ f0c, float* __restrict__ out) {
  __shared__ float red[256];
  const int o = blockIdx.x;
  float s = 0.0f;
  for (int n = threadIdx.x; n < NTOT; n += 256) s += f0c[n * 32 + o];
  red[threadIdx.x] = s;
  __syncthreads();
  for (int w = 128; w > 0; w >>= 1) {
    if (threadIdx.x < w) red[threadIdx.x] += red[threadIdx.x + w];
    __syncthreads();
  }
  if (threadIdx.x == 0) out[o] = red[0] / (float)NTOT;
}

extern "C" void kernel_launch(void* const* d_in, const int* in_sizes, int n_in,
                              void* d_out, int out_size, void* d_ws, size_t ws_size,
                              hipStream_t stream) {
  const float* radii   = (const float*)d_in[0];
  const int*   nbr     = (const int*)d_in[1];
  const int*   charges = (const int*)d_in[2];
  const float* w1l[3] = {(const float*)d_in[3],  (const float*)d_in[8],  (const float*)d_in[13]};
  const float* b1l[3] = {(const float*)d_in[4],  (const float*)d_in[9],  (const float*)d_in[14]};
  const float* w2l[3] = {(const float*)d_in[5],  (const float*)d_in[10], (const float*)d_in[15]};
  const float* b2l[3] = {(const float*)d_in[6],  (const float*)d_in[11], (const float*)d_in[16]};
  const float* w3l[3] = {(const float*)d_in[7],  (const float*)d_in[12], (const float*)d_in[17]};

  char* ws = (char*)d_ws;
  size_t off = 0;
  float* f0a = (float*)(ws + off); off += (size_t)NTOT * 16 * 4;
  float* f1a = (float*)(ws + off); off += (size_t)NTOT * 24 * 4;
  float* f0b = (float*)(ws + off); off += (size_t)NTOT * 16 * 4;
  float* f1b = (float*)(ws + off); off += (size_t)NTOT * 24 * 4;
  float* f0c = (float*)(ws + off); off += (size_t)NTOT * 32 * 4;
  unsigned short* bt2  = (unsigned short*)(ws + off); off += (size_t)3 * 16384 * 2;
  unsigned short* bt31 = (unsigned short*)(ws + off); off += (size_t)8192 * 2;
  unsigned short* bt32 = (unsigned short*)(ws + off); off += (size_t)106496 * 2;
  unsigned short* bt33 = (unsigned short*)(ws + off); off += (size_t)98304 * 2;
  unsigned short* w1i1 = (unsigned short*)(ws + off); off += (size_t)4096 * 2;
  unsigned short* w1i2 = (unsigned short*)(ws + off); off += (size_t)4096 * 2;
  unsigned short* w1i3 = (unsigned short*)(ws + off); off += (size_t)4096 * 2;

  prep_all<<<1072, 256, 0, stream>>>(w2l[0], w2l[1], w2l[2], w3l[0], w3l[1], w3l[2],
                                     w1l[0], w1l[1], w1l[2], b1l[0], b1l[1], b1l[2],
                                     bt2, bt31, bt32, bt33, w1i1, w1i2, w1i3);

  constexpr int NBLK = EDGES / 64;   // 2500

  layer_fused<1, 0, 16, 8, 8><<<NBLK, 256, 0, stream>>>(
      radii, nbr, charges, nullptr, nullptr,
      w1i1, bt2, b2l[0], bt31, f0a, f1a);

  layer_fused<16, 8, 16, 8, 8><<<NBLK, 256, 0, stream>>>(
      radii, nbr, charges, f0a, f1a,
      w1i2, bt2 + 16384, b2l[1], bt32, f0b, f1b);

  layer_fused<16, 8, 32, 0, 0><<<NBLK, 256, 0, stream>>>(
      radii, nbr, charges, f0b, f1b,
      w1i3, bt2 + 32768, b2l[2], bt33, f0c, nullptr);

  reduce_kernel<<<32, 256, 0, stream>>>(f0c, (float*)d_out);
}